// Round 2
// baseline (4348.415 us; speedup 1.0000x reference)
//
#include <hip/hip_runtime.h>
#include <hip/hip_bf16.h>

// ---------------- problem constants ----------------
constexpr int NN = 100000;   // nodes
constexpr int NE = 3200000;  // edges
constexpr int CYC = 128;     // signal channels

// ---------------- workspace layout (bytes) ----------------
#define OFF_W1T    0u          // [512][128] bf16 = 131072
#define OFF_W2T    131072u     // [16][512]  bf16 = 16384
#define OFF_B1E    147456u     // [512] f32 = 2048
#define OFF_SMALL  149504u     // 516 f32 (padded)
#define OFF_W34    151808u     // [20][128] f32 = 10240
#define OFF_B34    162048u     // [128] f32 = 512
#define OFF_XL     163840u     // [N][20] f32 = 8000000
#define OFF_XR     8163840u    // [N][20] f32 = 8000000
#define OFF_ALPHA  16163840u   // [E][2] f32 = 25600000
#define OFF_MENC   41763840u   // [N][2] u32 = 800000
#define OFF_DEN    42563840u   // [N][2] f32 = 800000
#define OFF_OUT20  43363840u   // [N][20] f32 = 8000000
#define OFF_FLAGS  51363840u   // 2 ints: [0]=floats-are-f32, [1]=mask-is-bytes
// total = 51363904 bytes

// smallf float offsets
#define SF_WLR 0    // [10][40]: cols 0..19 = Wl, 20..39 = Wr
#define SF_BLR 400  // [40]
#define SF_ATT 440  // [20] (h*10+c)
#define SF_WE  460  // [20]
#define SF_GB  480  // [20]
#define SF_B2  500  // [16]

typedef __attribute__((ext_vector_type(8))) short bf16x8;
typedef __attribute__((ext_vector_type(4))) float f32x4;

__device__ __forceinline__ float bfu(unsigned short x) {
  return __uint_as_float(((unsigned)x) << 16);
}
__device__ __forceinline__ short f2bf(float f) {
  __hip_bfloat16 h = __float2bfloat16(f);
  return *reinterpret_cast<short*>(&h);
}
// generic float load: f32 buffer or bf16 buffer, per runtime flag
__device__ __forceinline__ float LD(const void* p, long i, int f32f) {
  return f32f ? ((const float*)p)[i] : bfu(((const unsigned short*)p)[i]);
}
__device__ __forceinline__ unsigned encf(float f) {
  unsigned b = __float_as_uint(f);
  return (b & 0x80000000u) ? ~b : (b | 0x80000000u);
}
__device__ __forceinline__ float decf(unsigned u) {
  unsigned b = (u & 0x80000000u) ? (u & 0x7fffffffu) : ~u;
  return __uint_as_float(b);
}

// ---------------- dtype detection ----------------
// If the float buffers are f32 and we misread them as bf16, the low u16 of each
// f32 word is random mantissa bits -> huge/NaN exponents ~1/3 of the time.
// Genuine bf16 glorot weights (|x|<=0.11) never have exponent field >= 170.
__global__ void kDetect(const unsigned short* __restrict__ W1u,
                        const unsigned* __restrict__ masku,
                        int* __restrict__ flags) {
  if (threadIdx.x == 0) {
    int big = 0;
    for (int i = 0; i < 512; i++) {
      unsigned e = (W1u[i] >> 7) & 0xFF;
      if (e >= 170) big++;
    }
    flags[0] = (big >= 4) ? 1 : 0;
    int bytes = 0;
    for (int i = 0; i < 256; i++) if (masku[i] & ~1u) bytes = 1;
    flags[1] = bytes;
  }
}

// ---------------- precompute: folded/transposed weights ----------------
__global__ __launch_bounds__(256) void kPrep(
    const void* __restrict__ W1, const void* __restrict__ b1,
    const void* __restrict__ gamma, const void* __restrict__ beta,
    const void* __restrict__ W2, const void* __restrict__ b2,
    const void* __restrict__ Wl, const void* __restrict__ bl,
    const void* __restrict__ Wr, const void* __restrict__ br,
    const void* __restrict__ We, const void* __restrict__ att,
    const void* __restrict__ gbias, const void* __restrict__ W3,
    const void* __restrict__ b3, const void* __restrict__ W4,
    const void* __restrict__ b4, const int* __restrict__ flags,
    short* __restrict__ W1T, float* __restrict__ b1eff, short* __restrict__ W2T,
    float* __restrict__ smallf, float* __restrict__ W34, float* __restrict__ b34)
{
  const int f32f = flags[0];
  int tid = blockIdx.x * 256 + threadIdx.x;
  const float rs = 0.999995000037f;  // 1/sqrt(1+1e-5)
  if (tid < 65536) {
    int j = tid >> 7, k = tid & 127;
    float s = LD(gamma, j, f32f) * rs;
    W1T[j * 128 + k] = f2bf(LD(W1, k * 512 + j, f32f) * s);
    if (k == 0) b1eff[j] = LD(b1, j, f32f) * s + LD(beta, j, f32f);
  } else if (tid < 73728) {
    int i = tid - 65536;
    int c = i >> 9, k = i & 511;
    W2T[c * 512 + k] = (c < 10) ? f2bf(LD(W2, k * 10 + c, f32f)) : (short)0;
  } else if (tid < 76288) {
    int i = tid - 73728;
    int j = i >> 7, t = i & 127;
    float acc = 0.f;
    for (int k = 0; k < 512; k++) acc += LD(W3, j * 512 + k, f32f) * LD(W4, k * 128 + t, f32f);
    W34[j * 128 + t] = acc;
  } else if (tid < 76416) {
    int t = tid - 76288;
    float acc = LD(b4, t, f32f);
    for (int k = 0; k < 512; k++) acc += LD(b3, k, f32f) * LD(W4, k * 128 + t, f32f);
    b34[t] = acc;
  } else if (tid < 76932) {
    int i = tid - 76416;
    if (i < 400) {
      int c = i / 40, o = i % 40;
      smallf[SF_WLR + i] = (o < 20) ? LD(Wl, c * 20 + o, f32f) : LD(Wr, c * 20 + (o - 20), f32f);
    } else if (i < 440) {
      int o = i - 400;
      smallf[SF_BLR + o] = (o < 20) ? LD(bl, o, f32f) : LD(br, o - 20, f32f);
    } else if (i < 460) {
      smallf[SF_ATT + (i - 440)] = LD(att, i - 440, f32f);
    } else if (i < 480) {
      smallf[SF_WE + (i - 460)] = LD(We, i - 460, f32f);
    } else if (i < 500) {
      smallf[SF_GB + (i - 480)] = LD(gbias, i - 480, f32f);
    } else {
      int c = i - 500;
      smallf[SF_B2 + c] = (c < 10) ? LD(b2, c, f32f) : 0.f;
    }
  }
}

// ---------------- fused mlp_in + GAT linear transforms ----------------
// block = 256 (4 waves), each wave owns 16 node rows; grid = ceil(N/64)
__global__ __launch_bounds__(256) void kA(
    const void* __restrict__ sig, const void* __restrict__ mask,
    const short* __restrict__ W1T, const float* __restrict__ b1eff,
    const short* __restrict__ W2T, const float* __restrict__ smallf,
    const int* __restrict__ flags,
    float* __restrict__ xl, float* __restrict__ xr)
{
  __shared__ short h1[4][16][520];   // per-wave h1 tile (bf16)
  __shared__ float xh[4][16][12];    // per-wave x_hid tile
  __shared__ float sWlr[400];
  __shared__ float sblr[40];
  __shared__ float sb1[512];
  __shared__ float sb2[16];

  const int f32f = flags[0];
  const int mk8  = flags[1];
  int t = threadIdx.x;
  for (int i = t; i < 512; i += 256) sb1[i] = b1eff[i];
  for (int i = t; i < 400; i += 256) sWlr[i] = smallf[SF_WLR + i];
  if (t < 40) sblr[t] = smallf[SF_BLR + t];
  if (t < 16) sb2[t] = smallf[SF_B2 + t];
  __syncthreads();

  int w = t >> 6, l = t & 63;
  int lrow = l & 15, quad = l >> 4;
  int row0 = blockIdx.x * 64 + w * 16;
  if (row0 + 16 > NN) row0 = NN - 16;  // tail: duplicate-compute (idempotent stores)
  int arow = row0 + lrow;

  bool mbit = mk8 ? (((const unsigned char*)mask)[arow] != 0)
                  : (((const int*)mask)[arow] != 0);
  bool keep = !mbit;  // x = signal * (~mask)

  bf16x8 zz = {0, 0, 0, 0, 0, 0, 0, 0};
  bf16x8 af[4];
  if (!keep) {
#pragma unroll
    for (int kt = 0; kt < 4; kt++) af[kt] = zz;
  } else if (f32f) {
    const float4* Sf = (const float4*)((const float*)sig + (size_t)arow * CYC);
#pragma unroll
    for (int kt = 0; kt < 4; kt++) {
      float4 x0 = Sf[kt * 8 + quad * 2];
      float4 x1 = Sf[kt * 8 + quad * 2 + 1];
      bf16x8 v;
      v[0] = f2bf(x0.x); v[1] = f2bf(x0.y); v[2] = f2bf(x0.z); v[3] = f2bf(x0.w);
      v[4] = f2bf(x1.x); v[5] = f2bf(x1.y); v[6] = f2bf(x1.z); v[7] = f2bf(x1.w);
      af[kt] = v;
    }
  } else {
    const bf16x8* Ap = (const bf16x8*)((const unsigned short*)sig + (size_t)arow * CYC);
#pragma unroll
    for (int kt = 0; kt < 4; kt++) af[kt] = Ap[kt * 4 + quad];
  }

  // GEMM1: [16 rows x 128] @ [128 x 512]
  f32x4 acc[32];
#pragma unroll
  for (int ct = 0; ct < 32; ct++) acc[ct] = (f32x4){0.f, 0.f, 0.f, 0.f};
  const bf16x8* Bp = (const bf16x8*)W1T;
#pragma unroll
  for (int kt = 0; kt < 4; kt++) {
#pragma unroll
    for (int ct = 0; ct < 32; ct++) {
      bf16x8 bv = Bp[(ct * 16 + lrow) * 16 + kt * 4 + quad];
      acc[ct] = __builtin_amdgcn_mfma_f32_16x16x32_bf16(af[kt], bv, acc[ct], 0, 0, 0);
    }
  }
  // bias + ReLU -> h1 (bf16) in LDS
#pragma unroll
  for (int ct = 0; ct < 32; ct++) {
    int col = ct * 16 + lrow;
    float bb = sb1[col];
#pragma unroll
    for (int r = 0; r < 4; r++) {
      float v = fmaxf(acc[ct][r] + bb, 0.f);
      h1[w][quad * 4 + r][col] = f2bf(v);
    }
  }
  __syncthreads();

  // GEMM2: [16 x 512] @ [512 x 16(pad of 10)]
  f32x4 a2acc = (f32x4){0.f, 0.f, 0.f, 0.f};
  const bf16x8* B2p = (const bf16x8*)W2T;
#pragma unroll
  for (int kt = 0; kt < 16; kt++) {
    bf16x8 a2 = *(const bf16x8*)&h1[w][lrow][kt * 32 + quad * 8];
    bf16x8 b2v = B2p[lrow * 64 + kt * 4 + quad];
    a2acc = __builtin_amdgcn_mfma_f32_16x16x32_bf16(a2, b2v, a2acc, 0, 0, 0);
  }
  if (lrow < 10) {
    float bb = sb2[lrow];
#pragma unroll
    for (int r = 0; r < 4; r++) xh[w][quad * 4 + r][lrow] = a2acc[r] + bb;
  }
  __syncthreads();

  // xl = xh@Wl + bl, xr = xh@Wr + br : 16 rows x 40 outputs = 640 items/wave
#pragma unroll
  for (int ii = 0; ii < 10; ii++) {
    int item = ii * 64 + l;
    int row = item & 15, o = item >> 4;
    float v = sblr[o];
#pragma unroll
    for (int c = 0; c < 10; c++) v += xh[w][row][c] * sWlr[c * 40 + o];
    int gr = row0 + row;
    if (o < 20) xl[(size_t)gr * 20 + o] = v;
    else        xr[(size_t)gr * 20 + (o - 20)] = v;
  }
}

// ---------------- edge pass 1: alpha + segment max ----------------
__global__ __launch_bounds__(256) void kE1(
    const int* __restrict__ ei, const void* __restrict__ ew,
    const float* __restrict__ xl, const float* __restrict__ xr,
    const float* __restrict__ smallf, const int* __restrict__ flags,
    float2* __restrict__ alpha, unsigned* __restrict__ menc)
{
  __shared__ float sAtt[20], sWe[20];
  const int f32f = flags[0];
  int t = threadIdx.x;
  if (t < 20) { sAtt[t] = smallf[SF_ATT + t]; sWe[t] = smallf[SF_WE + t]; }
  __syncthreads();
  int e = blockIdx.x * 256 + t;
  if (e >= NE) return;
  int src = ei[e], dst = ei[NE + e];
  float w = LD(ew, e, f32f);
  const float4* pl = (const float4*)(xl + (size_t)src * 20);
  const float4* pr = (const float4*)(xr + (size_t)dst * 20);
  float vl[20], vr[20];
#pragma unroll
  for (int i = 0; i < 5; i++) {
    float4 a = pl[i], b = pr[i];
    vl[i * 4] = a.x; vl[i * 4 + 1] = a.y; vl[i * 4 + 2] = a.z; vl[i * 4 + 3] = a.w;
    vr[i * 4] = b.x; vr[i * 4 + 1] = b.y; vr[i * 4 + 2] = b.z; vr[i * 4 + 3] = b.w;
  }
  float a0 = 0.f, a1 = 0.f;
#pragma unroll
  for (int i = 0; i < 20; i++) {
    float v = vl[i] + vr[i] + w * sWe[i];
    v = (v > 0.f) ? v : 0.2f * v;  // leaky_relu 0.2
    if (i < 10) a0 += v * sAtt[i]; else a1 += v * sAtt[i];
  }
  alpha[e] = make_float2(a0, a1);
  atomicMax(&menc[dst * 2], encf(a0));
  atomicMax(&menc[dst * 2 + 1], encf(a1));
}

// ---------------- edge pass 2: exp + weighted aggregation ----------------
__global__ __launch_bounds__(256) void kE2(
    const int* __restrict__ ei, const float* __restrict__ xl,
    const float2* __restrict__ alpha, const unsigned* __restrict__ menc,
    float* __restrict__ den, float* __restrict__ outacc)
{
  int e = blockIdx.x * 256 + threadIdx.x;
  if (e >= NE) return;
  int src = ei[e], dst = ei[NE + e];
  float2 a = alpha[e];
  float m0 = decf(menc[dst * 2]), m1 = decf(menc[dst * 2 + 1]);
  float e0 = __expf(a.x - m0), e1 = __expf(a.y - m1);
  __hip_atomic_fetch_add(&den[dst * 2], e0, __ATOMIC_RELAXED, __HIP_MEMORY_SCOPE_AGENT);
  __hip_atomic_fetch_add(&den[dst * 2 + 1], e1, __ATOMIC_RELAXED, __HIP_MEMORY_SCOPE_AGENT);
  const float4* pl = (const float4*)(xl + (size_t)src * 20);
  float vl[20];
#pragma unroll
  for (int i = 0; i < 5; i++) {
    float4 v = pl[i];
    vl[i * 4] = v.x; vl[i * 4 + 1] = v.y; vl[i * 4 + 2] = v.z; vl[i * 4 + 3] = v.w;
  }
#pragma unroll
  for (int i = 0; i < 20; i++) {
    float s = (i < 10) ? e0 : e1;
    __hip_atomic_fetch_add(&outacc[(size_t)dst * 20 + i], s * vl[i],
                           __ATOMIC_RELAXED, __HIP_MEMORY_SCOPE_AGENT);
  }
}

// ---------------- final: normalize + bias + collapsed mlp_out/out_linear ----------------
__global__ __launch_bounds__(256) void kN2(
    const float* __restrict__ outacc, const float* __restrict__ den,
    const float* __restrict__ smallf, const float* __restrict__ W34,
    const float* __restrict__ b34, const int* __restrict__ flags,
    void* __restrict__ out)
{
  __shared__ float sW[2560];
  __shared__ float sb[128];
  __shared__ float sg[2][20];
  const int f32f = flags[0];
  int t = threadIdx.x;
  for (int i = t; i < 2560; i += 256) sW[i] = W34[i];
  if (t < 128) sb[t] = b34[t];
  int half = t >> 7, col = t & 127;
  int n = blockIdx.x * 2 + half;
  if (col < 20) {
    int j = col;
    float d = den[n * 2 + (j >= 10 ? 1 : 0)] + 1e-16f;
    sg[half][j] = outacc[(size_t)n * 20 + j] / d + smallf[SF_GB + j];
  }
  __syncthreads();
  float v = sb[col];
#pragma unroll
  for (int j = 0; j < 20; j++) v += sg[half][j] * sW[j * 128 + col];
  if (f32f) ((float*)out)[(size_t)n * 128 + col] = v;
  else ((unsigned short*)out)[(size_t)n * 128 + col] = (unsigned short)f2bf(v);
}

extern "C" void kernel_launch(void* const* d_in, const int* in_sizes, int n_in,
                              void* d_out, int out_size, void* d_ws, size_t ws_size,
                              hipStream_t stream) {
  (void)in_sizes; (void)n_in; (void)out_size; (void)ws_size;
  const void* sig  = d_in[0];
  const int*  ei   = (const int*)d_in[1];
  const void* ew   = d_in[2];
  const void* mask = d_in[3];
  const void* W1   = d_in[4];
  const void* b1   = d_in[5];
  const void* gam  = d_in[6];
  const void* bet  = d_in[7];
  const void* W2   = d_in[8];
  const void* b2   = d_in[9];
  const void* Wl   = d_in[10];
  const void* bl   = d_in[11];
  const void* Wr   = d_in[12];
  const void* br   = d_in[13];
  const void* We   = d_in[14];
  const void* att  = d_in[15];
  const void* gb   = d_in[16];
  const void* W3   = d_in[17];
  const void* b3   = d_in[18];
  const void* W4   = d_in[19];
  const void* b4   = d_in[20];

  char* ws = (char*)d_ws;
  short*  W1T    = (short*)(ws + OFF_W1T);
  short*  W2T    = (short*)(ws + OFF_W2T);
  float*  b1eff  = (float*)(ws + OFF_B1E);
  float*  smallf = (float*)(ws + OFF_SMALL);
  float*  W34    = (float*)(ws + OFF_W34);
  float*  b34    = (float*)(ws + OFF_B34);
  float*  xl     = (float*)(ws + OFF_XL);
  float*  xr     = (float*)(ws + OFF_XR);
  float2* alpha  = (float2*)(ws + OFF_ALPHA);
  unsigned* menc = (unsigned*)(ws + OFF_MENC);
  float*  den    = (float*)(ws + OFF_DEN);
  float*  outacc = (float*)(ws + OFF_OUT20);
  int*    flags  = (int*)(ws + OFF_FLAGS);

  hipMemsetAsync(ws + OFF_MENC, 0, 9600000, stream);

  kDetect<<<1, 64, 0, stream>>>((const unsigned short*)W1, (const unsigned*)mask, flags);
  kPrep<<<301, 256, 0, stream>>>(W1, b1, gam, bet, W2, b2, Wl, bl, Wr, br, We, att,
                                 gb, W3, b3, W4, b4, flags, W1T, b1eff, W2T, smallf, W34, b34);
  kA<<<(NN + 63) / 64, 256, 0, stream>>>(sig, mask, W1T, b1eff, W2T, smallf, flags, xl, xr);
  kE1<<<NE / 256, 256, 0, stream>>>(ei, ew, xl, xr, smallf, flags, alpha, menc);
  kE2<<<NE / 256, 256, 0, stream>>>(ei, xl, alpha, menc, den, outacc);
  kN2<<<NN / 2, 256, 0, stream>>>(outacc, den, smallf, W34, b34, flags, d_out);
}

// Round 3
// 965.889 us; speedup vs baseline: 4.5020x; 4.5020x over previous
//
#include <hip/hip_runtime.h>
#include <hip/hip_bf16.h>

// ---------------- problem constants ----------------
constexpr int NN = 100000;   // nodes
constexpr int NE = 3200000;  // edges
constexpr int CYC = 128;     // signal channels

// ---------------- workspace layout (bytes) ----------------
#define OFF_W1T    0u          // [512][128] bf16
#define OFF_W2T    131072u     // [16][512]  bf16
#define OFF_B1E    147456u     // [512] f32
#define OFF_SMALL  149504u     // 516 f32 (padded)
#define OFF_W34    151808u     // [20][128] f32
#define OFF_B34    162048u     // [128] f32
#define OFF_FLAGS  162560u     // ints
#define OFF_XL     163840u     // [N][20] f32 = 8,000,000
#define OFF_XR     8163840u    // [N][20] f32 = 8,000,000
#define OFF_DEG    16163840u   // [N] int = 400,000
#define OFF_OFFS   16563840u   // [N+1] int (padded to 400,064)
#define OFF_CUR    16963904u   // [N] int = 400,000
#define OFF_BS     17363904u   // scan block sums (padded 4,160)
#define OFF_CSR    17368064u   // [E] int2 {src, ew_bits} = 25,600,000
// total = 42,968,064 bytes (< round-2 footprint, which fit)

// smallf float offsets
#define SF_WLR 0    // [10][40]: cols 0..19 = Wl, 20..39 = Wr
#define SF_BLR 400  // [40]
#define SF_ATT 440  // [20] (h*10+c)
#define SF_WE  460  // [20]
#define SF_GB  480  // [20]
#define SF_B2  500  // [16]

typedef __attribute__((ext_vector_type(8))) short bf16x8;
typedef __attribute__((ext_vector_type(4))) float f32x4;

__device__ __forceinline__ float bfu(unsigned short x) {
  return __uint_as_float(((unsigned)x) << 16);
}
__device__ __forceinline__ short f2bf(float f) {
  __hip_bfloat16 h = __float2bfloat16(f);
  return *reinterpret_cast<short*>(&h);
}
__device__ __forceinline__ float LD(const void* p, long i, int f32f) {
  return f32f ? ((const float*)p)[i] : bfu(((const unsigned short*)p)[i]);
}

// ---------------- dtype detection (see round-1 notes) ----------------
__global__ void kDetect(const unsigned short* __restrict__ W1u,
                        const unsigned* __restrict__ masku,
                        int* __restrict__ flags) {
  if (threadIdx.x == 0) {
    int big = 0;
    for (int i = 0; i < 512; i++) {
      unsigned e = (W1u[i] >> 7) & 0xFF;
      if (e >= 170) big++;
    }
    flags[0] = (big >= 4) ? 1 : 0;
    int bytes = 0;
    for (int i = 0; i < 256; i++) if (masku[i] & ~1u) bytes = 1;
    flags[1] = bytes;
  }
}

// ---------------- precompute: folded/transposed weights ----------------
__global__ __launch_bounds__(256) void kPrep(
    const void* __restrict__ W1, const void* __restrict__ b1,
    const void* __restrict__ gamma, const void* __restrict__ beta,
    const void* __restrict__ W2, const void* __restrict__ b2,
    const void* __restrict__ Wl, const void* __restrict__ bl,
    const void* __restrict__ Wr, const void* __restrict__ br,
    const void* __restrict__ We, const void* __restrict__ att,
    const void* __restrict__ gbias, const void* __restrict__ W3,
    const void* __restrict__ b3, const void* __restrict__ W4,
    const void* __restrict__ b4, const int* __restrict__ flags,
    short* __restrict__ W1T, float* __restrict__ b1eff, short* __restrict__ W2T,
    float* __restrict__ smallf, float* __restrict__ W34, float* __restrict__ b34)
{
  const int f32f = flags[0];
  int tid = blockIdx.x * 256 + threadIdx.x;
  const float rs = 0.999995000037f;  // 1/sqrt(1+1e-5)
  if (tid < 65536) {
    int j = tid >> 7, k = tid & 127;
    float s = LD(gamma, j, f32f) * rs;
    W1T[j * 128 + k] = f2bf(LD(W1, k * 512 + j, f32f) * s);
    if (k == 0) b1eff[j] = LD(b1, j, f32f) * s + LD(beta, j, f32f);
  } else if (tid < 73728) {
    int i = tid - 65536;
    int c = i >> 9, k = i & 511;
    W2T[c * 512 + k] = (c < 10) ? f2bf(LD(W2, k * 10 + c, f32f)) : (short)0;
  } else if (tid < 76288) {
    int i = tid - 73728;
    int j = i >> 7, t = i & 127;
    float acc = 0.f;
    for (int k = 0; k < 512; k++) acc += LD(W3, j * 512 + k, f32f) * LD(W4, k * 128 + t, f32f);
    W34[j * 128 + t] = acc;
  } else if (tid < 76416) {
    int t = tid - 76288;
    float acc = LD(b4, t, f32f);
    for (int k = 0; k < 512; k++) acc += LD(b3, k, f32f) * LD(W4, k * 128 + t, f32f);
    b34[t] = acc;
  } else if (tid < 76932) {
    int i = tid - 76416;
    if (i < 400) {
      int c = i / 40, o = i % 40;
      smallf[SF_WLR + i] = (o < 20) ? LD(Wl, c * 20 + o, f32f) : LD(Wr, c * 20 + (o - 20), f32f);
    } else if (i < 440) {
      int o = i - 400;
      smallf[SF_BLR + o] = (o < 20) ? LD(bl, o, f32f) : LD(br, o - 20, f32f);
    } else if (i < 460) {
      smallf[SF_ATT + (i - 440)] = LD(att, i - 440, f32f);
    } else if (i < 480) {
      smallf[SF_WE + (i - 460)] = LD(We, i - 460, f32f);
    } else if (i < 500) {
      smallf[SF_GB + (i - 480)] = LD(gbias, i - 480, f32f);
    } else {
      int c = i - 500;
      smallf[SF_B2 + c] = (c < 10) ? LD(b2, c, f32f) : 0.f;
    }
  }
}

// ---------------- fused mlp_in + GAT linear transforms (unchanged) ----------------
__global__ __launch_bounds__(256) void kA(
    const void* __restrict__ sig, const void* __restrict__ mask,
    const short* __restrict__ W1T, const float* __restrict__ b1eff,
    const short* __restrict__ W2T, const float* __restrict__ smallf,
    const int* __restrict__ flags,
    float* __restrict__ xl, float* __restrict__ xr)
{
  __shared__ short h1[4][16][520];
  __shared__ float xh[4][16][12];
  __shared__ float sWlr[400];
  __shared__ float sblr[40];
  __shared__ float sb1[512];
  __shared__ float sb2[16];

  const int f32f = flags[0];
  const int mk8  = flags[1];
  int t = threadIdx.x;
  for (int i = t; i < 512; i += 256) sb1[i] = b1eff[i];
  for (int i = t; i < 400; i += 256) sWlr[i] = smallf[SF_WLR + i];
  if (t < 40) sblr[t] = smallf[SF_BLR + t];
  if (t < 16) sb2[t] = smallf[SF_B2 + t];
  __syncthreads();

  int w = t >> 6, l = t & 63;
  int lrow = l & 15, quad = l >> 4;
  int row0 = blockIdx.x * 64 + w * 16;
  if (row0 + 16 > NN) row0 = NN - 16;
  int arow = row0 + lrow;

  bool mbit = mk8 ? (((const unsigned char*)mask)[arow] != 0)
                  : (((const int*)mask)[arow] != 0);
  bool keep = !mbit;

  bf16x8 zz = {0, 0, 0, 0, 0, 0, 0, 0};
  bf16x8 af[4];
  if (!keep) {
#pragma unroll
    for (int kt = 0; kt < 4; kt++) af[kt] = zz;
  } else if (f32f) {
    const float4* Sf = (const float4*)((const float*)sig + (size_t)arow * CYC);
#pragma unroll
    for (int kt = 0; kt < 4; kt++) {
      float4 x0 = Sf[kt * 8 + quad * 2];
      float4 x1 = Sf[kt * 8 + quad * 2 + 1];
      bf16x8 v;
      v[0] = f2bf(x0.x); v[1] = f2bf(x0.y); v[2] = f2bf(x0.z); v[3] = f2bf(x0.w);
      v[4] = f2bf(x1.x); v[5] = f2bf(x1.y); v[6] = f2bf(x1.z); v[7] = f2bf(x1.w);
      af[kt] = v;
    }
  } else {
    const bf16x8* Ap = (const bf16x8*)((const unsigned short*)sig + (size_t)arow * CYC);
#pragma unroll
    for (int kt = 0; kt < 4; kt++) af[kt] = Ap[kt * 4 + quad];
  }

  f32x4 acc[32];
#pragma unroll
  for (int ct = 0; ct < 32; ct++) acc[ct] = (f32x4){0.f, 0.f, 0.f, 0.f};
  const bf16x8* Bp = (const bf16x8*)W1T;
#pragma unroll
  for (int kt = 0; kt < 4; kt++) {
#pragma unroll
    for (int ct = 0; ct < 32; ct++) {
      bf16x8 bv = Bp[(ct * 16 + lrow) * 16 + kt * 4 + quad];
      acc[ct] = __builtin_amdgcn_mfma_f32_16x16x32_bf16(af[kt], bv, acc[ct], 0, 0, 0);
    }
  }
#pragma unroll
  for (int ct = 0; ct < 32; ct++) {
    int col = ct * 16 + lrow;
    float bb = sb1[col];
#pragma unroll
    for (int r = 0; r < 4; r++) {
      float v = fmaxf(acc[ct][r] + bb, 0.f);
      h1[w][quad * 4 + r][col] = f2bf(v);
    }
  }
  __syncthreads();

  f32x4 a2acc = (f32x4){0.f, 0.f, 0.f, 0.f};
  const bf16x8* B2p = (const bf16x8*)W2T;
#pragma unroll
  for (int kt = 0; kt < 16; kt++) {
    bf16x8 a2 = *(const bf16x8*)&h1[w][lrow][kt * 32 + quad * 8];
    bf16x8 b2v = B2p[lrow * 64 + kt * 4 + quad];
    a2acc = __builtin_amdgcn_mfma_f32_16x16x32_bf16(a2, b2v, a2acc, 0, 0, 0);
  }
  if (lrow < 10) {
    float bb = sb2[lrow];
#pragma unroll
    for (int r = 0; r < 4; r++) xh[w][quad * 4 + r][lrow] = a2acc[r] + bb;
  }
  __syncthreads();

#pragma unroll
  for (int ii = 0; ii < 10; ii++) {
    int item = ii * 64 + l;
    int row = item & 15, o = item >> 4;
    float v = sblr[o];
#pragma unroll
    for (int c = 0; c < 10; c++) v += xh[w][row][c] * sWlr[c * 40 + o];
    int gr = row0 + row;
    if (o < 20) xl[(size_t)gr * 20 + o] = v;
    else        xr[(size_t)gr * 20 + (o - 20)] = v;
  }
}

// ---------------- CSR build: histogram ----------------
__global__ __launch_bounds__(256) void kHist(const int* __restrict__ ei,
                                             int* __restrict__ deg) {
  int e = blockIdx.x * 256 + threadIdx.x;
  if (e >= NE) return;
  atomicAdd(&deg[ei[NE + e]], 1);
}

// ---------------- CSR build: scan (3 kernels) ----------------
// kScan1: each block scans 1024 elems (4/thread), writes within-block exclusive
// prefix to offs, block total to bsum.
__global__ __launch_bounds__(256) void kScan1(const int* __restrict__ deg,
                                              int* __restrict__ offs,
                                              int* __restrict__ bsum) {
  __shared__ int sS[256];
  int t = threadIdx.x;
  int base = blockIdx.x * 1024 + t * 4;
  int d0 = (base     < NN) ? deg[base]     : 0;
  int d1 = (base + 1 < NN) ? deg[base + 1] : 0;
  int d2 = (base + 2 < NN) ? deg[base + 2] : 0;
  int d3 = (base + 3 < NN) ? deg[base + 3] : 0;
  int tsum = d0 + d1 + d2 + d3;
  sS[t] = tsum;
  __syncthreads();
  for (int o = 1; o < 256; o <<= 1) {
    int v = (t >= o) ? sS[t - o] : 0;
    __syncthreads();
    sS[t] += v;
    __syncthreads();
  }
  int ex = sS[t] - tsum;
  if (base     < NN) offs[base]     = ex;
  if (base + 1 < NN) offs[base + 1] = ex + d0;
  if (base + 2 < NN) offs[base + 2] = ex + d0 + d1;
  if (base + 3 < NN) offs[base + 3] = ex + d0 + d1 + d2;
  if (t == 255) bsum[blockIdx.x] = sS[255];
}

__global__ __launch_bounds__(128) void kScan2(int* __restrict__ bsum, int nb) {
  __shared__ int sS[128];
  int t = threadIdx.x;
  int v = (t < nb) ? bsum[t] : 0;
  sS[t] = v;
  __syncthreads();
  for (int o = 1; o < 128; o <<= 1) {
    int u = (t >= o) ? sS[t - o] : 0;
    __syncthreads();
    sS[t] += u;
    __syncthreads();
  }
  if (t < nb) bsum[t] = sS[t] - v;
}

__global__ __launch_bounds__(256) void kScan3(int* __restrict__ offs,
                                              const int* __restrict__ bsum,
                                              int* __restrict__ cur) {
  int i = blockIdx.x * 256 + threadIdx.x;
  if (i < NN) {
    int v = offs[i] + bsum[i >> 10];
    offs[i] = v;
    cur[i] = v;
  }
  if (i == 0) offs[NN] = NE;
}

// ---------------- CSR build: scatter ----------------
__global__ __launch_bounds__(256) void kScatter(const int* __restrict__ ei,
                                                const void* __restrict__ ew,
                                                const int* __restrict__ flags,
                                                int* __restrict__ cur,
                                                int2* __restrict__ csr) {
  const int f32f = flags[0];
  int e = blockIdx.x * 256 + threadIdx.x;
  if (e >= NE) return;
  int src = ei[e], dst = ei[NE + e];
  float w = LD(ew, e, f32f);
  int pos = atomicAdd(&cur[dst], 1);
  csr[pos] = make_int2(src, __float_as_int(w));
}

// ---------------- fused gather + online softmax + aggregate + output GEMM ----------------
// one wave per dst node; block 256 = 4 nodes; grid 25000
__global__ __launch_bounds__(256) void kAgg(
    const int* __restrict__ offs, const int2* __restrict__ csr,
    const float* __restrict__ xl, const float* __restrict__ xr,
    const float* __restrict__ smallf, const float* __restrict__ W34,
    const float* __restrict__ b34, const int* __restrict__ flags,
    void* __restrict__ out)
{
  __shared__ float sW[2560];
  __shared__ float sb[128];
  __shared__ float sAtt[20], sWe[20], sGb[20];
  const int f32f = flags[0];
  int t = threadIdx.x;
  for (int i = t; i < 2560; i += 256) sW[i] = W34[i];
  if (t < 128) sb[t] = b34[t];
  if (t < 20) { sAtt[t] = smallf[SF_ATT + t]; sWe[t] = smallf[SF_WE + t]; sGb[t] = smallf[SF_GB + t]; }
  __syncthreads();

  int w = t >> 6, lane = t & 63;
  int n = blockIdx.x * 4 + w;   // grid*4 == NN exactly

  int start = offs[n], end = offs[n + 1];

  // xr[n] broadcast into registers
  float vr[20];
  {
    const float4* pr = (const float4*)(xr + (size_t)n * 20);
#pragma unroll
    for (int i = 0; i < 5; i++) {
      float4 b = pr[i];
      vr[i * 4] = b.x; vr[i * 4 + 1] = b.y; vr[i * 4 + 2] = b.z; vr[i * 4 + 3] = b.w;
    }
  }

  // per-lane online-softmax state (2 heads)
  float m0 = -1e30f, l0 = 0.f, m1 = -1e30f, l1 = 0.f;
  float acc0[10], acc1[10];
#pragma unroll
  for (int c = 0; c < 10; c++) { acc0[c] = 0.f; acc1[c] = 0.f; }

  for (int i = start + lane; i < end; i += 64) {
    int2 eg = csr[i];
    int src = eg.x;
    float ww = __int_as_float(eg.y);
    const float4* pl = (const float4*)(xl + (size_t)src * 20);
    float vl[20];
#pragma unroll
    for (int k = 0; k < 5; k++) {
      float4 v = pl[k];
      vl[k * 4] = v.x; vl[k * 4 + 1] = v.y; vl[k * 4 + 2] = v.z; vl[k * 4 + 3] = v.w;
    }
    float a0 = 0.f, a1 = 0.f;
#pragma unroll
    for (int c = 0; c < 20; c++) {
      float v = vl[c] + vr[c] + ww * sWe[c];
      v = fmaxf(v, 0.2f * v);  // leaky_relu(0.2)
      if (c < 10) a0 += v * sAtt[c]; else a1 += v * sAtt[c];
    }
    // head 0
    {
      float mn = fmaxf(m0, a0);
      float corr = __expf(m0 - mn), p = __expf(a0 - mn);
      l0 = l0 * corr + p;
#pragma unroll
      for (int c = 0; c < 10; c++) acc0[c] = acc0[c] * corr + p * vl[c];
      m0 = mn;
    }
    // head 1
    {
      float mn = fmaxf(m1, a1);
      float corr = __expf(m1 - mn), p = __expf(a1 - mn);
      l1 = l1 * corr + p;
#pragma unroll
      for (int c = 0; c < 10; c++) acc1[c] = acc1[c] * corr + p * vl[10 + c];
      m1 = mn;
    }
  }

  // butterfly reduce across 64 lanes (all lanes converge to full state)
#pragma unroll
  for (int o = 1; o < 64; o <<= 1) {
    float mo = __shfl_xor(m0, o), lo = __shfl_xor(l0, o);
    float mn = fmaxf(m0, mo);
    float ca = __expf(m0 - mn), cb = __expf(mo - mn);
    l0 = l0 * ca + lo * cb;
#pragma unroll
    for (int c = 0; c < 10; c++) acc0[c] = acc0[c] * ca + __shfl_xor(acc0[c], o) * cb;
    m0 = mn;
    float mo1 = __shfl_xor(m1, o), lo1 = __shfl_xor(l1, o);
    float mn1 = fmaxf(m1, mo1);
    float da = __expf(m1 - mn1), db = __expf(mo1 - mn1);
    l1 = l1 * da + lo1 * db;
#pragma unroll
    for (int c = 0; c < 10; c++) acc1[c] = acc1[c] * da + __shfl_xor(acc1[c], o) * db;
    m1 = mn1;
  }

  // finalize: g[20] = acc/l + gat_bias   (degree-0: l=0 -> acc=0 -> g=bias)
  float g[20];
  float inv0 = 1.f / (l0 + 1e-16f), inv1 = 1.f / (l1 + 1e-16f);
#pragma unroll
  for (int c = 0; c < 10; c++) {
    g[c]      = acc0[c] * inv0 + sGb[c];
    g[10 + c] = acc1[c] * inv1 + sGb[10 + c];
  }

  // output GEMM row: each lane does 2 columns of out = g @ W34 + b34
  int col = lane * 2;
  float v0 = sb[col], v1 = sb[col + 1];
#pragma unroll
  for (int j = 0; j < 20; j++) {
    v0 += g[j] * sW[j * 128 + col];
    v1 += g[j] * sW[j * 128 + col + 1];
  }
  size_t oi = (size_t)n * 128 + col;
  if (f32f) {
    ((float2*)out)[oi / 2] = make_float2(v0, v1);
  } else {
    unsigned pk = (unsigned)(unsigned short)f2bf(v0) |
                  ((unsigned)(unsigned short)f2bf(v1) << 16);
    ((unsigned*)out)[oi / 2] = pk;
  }
}

extern "C" void kernel_launch(void* const* d_in, const int* in_sizes, int n_in,
                              void* d_out, int out_size, void* d_ws, size_t ws_size,
                              hipStream_t stream) {
  (void)in_sizes; (void)n_in; (void)out_size; (void)ws_size;
  const void* sig  = d_in[0];
  const int*  ei   = (const int*)d_in[1];
  const void* ew   = d_in[2];
  const void* mask = d_in[3];
  const void* W1   = d_in[4];
  const void* b1   = d_in[5];
  const void* gam  = d_in[6];
  const void* bet  = d_in[7];
  const void* W2   = d_in[8];
  const void* b2   = d_in[9];
  const void* Wl   = d_in[10];
  const void* bl   = d_in[11];
  const void* Wr   = d_in[12];
  const void* br   = d_in[13];
  const void* We   = d_in[14];
  const void* att  = d_in[15];
  const void* gb   = d_in[16];
  const void* W3   = d_in[17];
  const void* b3   = d_in[18];
  const void* W4   = d_in[19];
  const void* b4   = d_in[20];

  char* ws = (char*)d_ws;
  short* W1T    = (short*)(ws + OFF_W1T);
  short* W2T    = (short*)(ws + OFF_W2T);
  float* b1eff  = (float*)(ws + OFF_B1E);
  float* smallf = (float*)(ws + OFF_SMALL);
  float* W34    = (float*)(ws + OFF_W34);
  float* b34    = (float*)(ws + OFF_B34);
  int*   flags  = (int*)(ws + OFF_FLAGS);
  float* xl     = (float*)(ws + OFF_XL);
  float* xr     = (float*)(ws + OFF_XR);
  int*   deg    = (int*)(ws + OFF_DEG);
  int*   offs   = (int*)(ws + OFF_OFFS);
  int*   cur    = (int*)(ws + OFF_CUR);
  int*   bsum   = (int*)(ws + OFF_BS);
  int2*  csr    = (int2*)(ws + OFF_CSR);

  hipMemsetAsync(deg, 0, 400000, stream);

  kDetect<<<1, 64, 0, stream>>>((const unsigned short*)W1, (const unsigned*)mask, flags);
  kPrep<<<301, 256, 0, stream>>>(W1, b1, gam, bet, W2, b2, Wl, bl, Wr, br, We, att,
                                 gb, W3, b3, W4, b4, flags, W1T, b1eff, W2T, smallf, W34, b34);
  kA<<<(NN + 63) / 64, 256, 0, stream>>>(sig, mask, W1T, b1eff, W2T, smallf, flags, xl, xr);
  kHist<<<(NE + 255) / 256, 256, 0, stream>>>(ei, deg);
  kScan1<<<(NN + 1023) / 1024, 256, 0, stream>>>(deg, offs, bsum);
  kScan2<<<1, 128, 0, stream>>>(bsum, (NN + 1023) / 1024);
  kScan3<<<(NN + 255) / 256, 256, 0, stream>>>(offs, bsum, cur);
  kScatter<<<(NE + 255) / 256, 256, 0, stream>>>(ei, ew, flags, cur, csr);
  kAgg<<<NN / 4, 256, 0, stream>>>(offs, csr, xl, xr, smallf, W34, b34, flags, d_out);
}

// Round 4
// 811.107 us; speedup vs baseline: 5.3611x; 1.1908x over previous
//
#include <hip/hip_runtime.h>
#include <hip/hip_bf16.h>

// ---------------- problem constants ----------------
constexpr int NN = 100000;   // nodes
constexpr int NE = 3200000;  // edges
constexpr int CYC = 128;     // signal channels
constexpr int NB = 391;      // buckets of 256 nodes: ceil(100000/256)
constexpr int EBLK = 256;    // edge-pass blocks
constexpr int ECHUNK = NE / EBLK;  // 12500 edges per block

// ---------------- workspace layout (bytes) ----------------
#define OFF_W1T    0u          // [512][128] bf16
#define OFF_W2T    131072u     // [16][512]  bf16
#define OFF_B1E    147456u     // [512] f32
#define OFF_SMALL  149504u     // 516 f32 (padded)
#define OFF_W34    151808u     // [20][128] f32
#define OFF_B34    162048u     // [128] f32
#define OFF_FLAGS  162560u     // ints
#define OFF_XL     163840u     // [N][20] f32 = 8,000,000
#define OFF_XR     8163840u    // [N][20] f32 = 8,000,000
#define OFF_GH     16163840u   // [NB][EBLK] int = 400,384
#define OFF_BB     16564224u   // [NB+1] int (padded 1600)
#define OFF_OFFS   16565824u   // [N+1] int (padded 400,064)
#define OFF_BIN    16965888u   // [E] int2 {packed, ew_bits} = 25,600,000 (becomes CSR in place)
// total = 42,565,888 bytes (< round-2 proven 51.4 MB)

// smallf float offsets
#define SF_WLR 0    // [10][40]: cols 0..19 = Wl, 20..39 = Wr
#define SF_BLR 400  // [40]
#define SF_ATT 440  // [20] (h*10+c)
#define SF_WE  460  // [20]
#define SF_GB  480  // [20]
#define SF_B2  500  // [16]

typedef __attribute__((ext_vector_type(8))) short bf16x8;
typedef __attribute__((ext_vector_type(4))) float f32x4;

__device__ __forceinline__ float bfu(unsigned short x) {
  return __uint_as_float(((unsigned)x) << 16);
}
__device__ __forceinline__ short f2bf(float f) {
  __hip_bfloat16 h = __float2bfloat16(f);
  return *reinterpret_cast<short*>(&h);
}
__device__ __forceinline__ float LD(const void* p, long i, int f32f) {
  return f32f ? ((const float*)p)[i] : bfu(((const unsigned short*)p)[i]);
}

// ---------------- dtype detection (wave-parallel) ----------------
__global__ void kDetect(const unsigned short* __restrict__ W1u,
                        const unsigned* __restrict__ masku,
                        int* __restrict__ flags) {
  int l = threadIdx.x;  // 64 lanes
  int big = 0;
#pragma unroll
  for (int k = 0; k < 8; k++) {
    unsigned e = (W1u[l * 8 + k] >> 7) & 0xFF;
    if (e >= 170) big++;
  }
  int byt = 0;
#pragma unroll
  for (int k = 0; k < 4; k++) if (masku[l * 4 + k] & ~1u) byt = 1;
#pragma unroll
  for (int o = 1; o < 64; o <<= 1) {
    big += __shfl_xor(big, o);
    byt |= __shfl_xor(byt, o);
  }
  if (l == 0) { flags[0] = (big >= 4) ? 1 : 0; flags[1] = byt; }
}

// ---------------- precompute: folded/transposed weights ----------------
__global__ __launch_bounds__(256) void kPrep(
    const void* __restrict__ W1, const void* __restrict__ b1,
    const void* __restrict__ gamma, const void* __restrict__ beta,
    const void* __restrict__ W2, const void* __restrict__ b2,
    const void* __restrict__ Wl, const void* __restrict__ bl,
    const void* __restrict__ Wr, const void* __restrict__ br,
    const void* __restrict__ We, const void* __restrict__ att,
    const void* __restrict__ gbias, const void* __restrict__ W3,
    const void* __restrict__ b3, const void* __restrict__ W4,
    const void* __restrict__ b4, const int* __restrict__ flags,
    short* __restrict__ W1T, float* __restrict__ b1eff, short* __restrict__ W2T,
    float* __restrict__ smallf, float* __restrict__ W34, float* __restrict__ b34)
{
  const int f32f = flags[0];
  int tid = blockIdx.x * 256 + threadIdx.x;
  const float rs = 0.999995000037f;  // 1/sqrt(1+1e-5)
  if (tid < 65536) {
    int j = tid >> 7, k = tid & 127;
    float s = LD(gamma, j, f32f) * rs;
    W1T[j * 128 + k] = f2bf(LD(W1, k * 512 + j, f32f) * s);
    if (k == 0) b1eff[j] = LD(b1, j, f32f) * s + LD(beta, j, f32f);
  } else if (tid < 73728) {
    int i = tid - 65536;
    int c = i >> 9, k = i & 511;
    W2T[c * 512 + k] = (c < 10) ? f2bf(LD(W2, k * 10 + c, f32f)) : (short)0;
  } else if (tid < 76288) {
    int i = tid - 73728;
    int j = i >> 7, t = i & 127;
    float acc = 0.f;
    for (int k = 0; k < 512; k++) acc += LD(W3, j * 512 + k, f32f) * LD(W4, k * 128 + t, f32f);
    W34[j * 128 + t] = acc;
  } else if (tid < 76416) {
    int t = tid - 76288;
    float acc = LD(b4, t, f32f);
    for (int k = 0; k < 512; k++) acc += LD(b3, k, f32f) * LD(W4, k * 128 + t, f32f);
    b34[t] = acc;
  } else if (tid < 76932) {
    int i = tid - 76416;
    if (i < 400) {
      int c = i / 40, o = i % 40;
      smallf[SF_WLR + i] = (o < 20) ? LD(Wl, c * 20 + o, f32f) : LD(Wr, c * 20 + (o - 20), f32f);
    } else if (i < 440) {
      int o = i - 400;
      smallf[SF_BLR + o] = (o < 20) ? LD(bl, o, f32f) : LD(br, o - 20, f32f);
    } else if (i < 460) {
      smallf[SF_ATT + (i - 440)] = LD(att, i - 440, f32f);
    } else if (i < 480) {
      smallf[SF_WE + (i - 460)] = LD(We, i - 460, f32f);
    } else if (i < 500) {
      smallf[SF_GB + (i - 480)] = LD(gbias, i - 480, f32f);
    } else {
      int c = i - 500;
      smallf[SF_B2 + c] = (c < 10) ? LD(b2, c, f32f) : 0.f;
    }
  }
}

// ---------------- fused mlp_in + GAT linear transforms (unchanged) ----------------
__global__ __launch_bounds__(256) void kA(
    const void* __restrict__ sig, const void* __restrict__ mask,
    const short* __restrict__ W1T, const float* __restrict__ b1eff,
    const short* __restrict__ W2T, const float* __restrict__ smallf,
    const int* __restrict__ flags,
    float* __restrict__ xl, float* __restrict__ xr)
{
  __shared__ short h1[4][16][520];
  __shared__ float xh[4][16][12];
  __shared__ float sWlr[400];
  __shared__ float sblr[40];
  __shared__ float sb1[512];
  __shared__ float sb2[16];

  const int f32f = flags[0];
  const int mk8  = flags[1];
  int t = threadIdx.x;
  for (int i = t; i < 512; i += 256) sb1[i] = b1eff[i];
  for (int i = t; i < 400; i += 256) sWlr[i] = smallf[SF_WLR + i];
  if (t < 40) sblr[t] = smallf[SF_BLR + t];
  if (t < 16) sb2[t] = smallf[SF_B2 + t];
  __syncthreads();

  int w = t >> 6, l = t & 63;
  int lrow = l & 15, quad = l >> 4;
  int row0 = blockIdx.x * 64 + w * 16;
  if (row0 + 16 > NN) row0 = NN - 16;
  int arow = row0 + lrow;

  bool mbit = mk8 ? (((const unsigned char*)mask)[arow] != 0)
                  : (((const int*)mask)[arow] != 0);
  bool keep = !mbit;

  bf16x8 zz = {0, 0, 0, 0, 0, 0, 0, 0};
  bf16x8 af[4];
  if (!keep) {
#pragma unroll
    for (int kt = 0; kt < 4; kt++) af[kt] = zz;
  } else if (f32f) {
    const float4* Sf = (const float4*)((const float*)sig + (size_t)arow * CYC);
#pragma unroll
    for (int kt = 0; kt < 4; kt++) {
      float4 x0 = Sf[kt * 8 + quad * 2];
      float4 x1 = Sf[kt * 8 + quad * 2 + 1];
      bf16x8 v;
      v[0] = f2bf(x0.x); v[1] = f2bf(x0.y); v[2] = f2bf(x0.z); v[3] = f2bf(x0.w);
      v[4] = f2bf(x1.x); v[5] = f2bf(x1.y); v[6] = f2bf(x1.z); v[7] = f2bf(x1.w);
      af[kt] = v;
    }
  } else {
    const bf16x8* Ap = (const bf16x8*)((const unsigned short*)sig + (size_t)arow * CYC);
#pragma unroll
    for (int kt = 0; kt < 4; kt++) af[kt] = Ap[kt * 4 + quad];
  }

  f32x4 acc[32];
#pragma unroll
  for (int ct = 0; ct < 32; ct++) acc[ct] = (f32x4){0.f, 0.f, 0.f, 0.f};
  const bf16x8* Bp = (const bf16x8*)W1T;
#pragma unroll
  for (int kt = 0; kt < 4; kt++) {
#pragma unroll
    for (int ct = 0; ct < 32; ct++) {
      bf16x8 bv = Bp[(ct * 16 + lrow) * 16 + kt * 4 + quad];
      acc[ct] = __builtin_amdgcn_mfma_f32_16x16x32_bf16(af[kt], bv, acc[ct], 0, 0, 0);
    }
  }
#pragma unroll
  for (int ct = 0; ct < 32; ct++) {
    int col = ct * 16 + lrow;
    float bb = sb1[col];
#pragma unroll
    for (int r = 0; r < 4; r++) {
      float v = fmaxf(acc[ct][r] + bb, 0.f);
      h1[w][quad * 4 + r][col] = f2bf(v);
    }
  }
  __syncthreads();

  f32x4 a2acc = (f32x4){0.f, 0.f, 0.f, 0.f};
  const bf16x8* B2p = (const bf16x8*)W2T;
#pragma unroll
  for (int kt = 0; kt < 16; kt++) {
    bf16x8 a2 = *(const bf16x8*)&h1[w][lrow][kt * 32 + quad * 8];
    bf16x8 b2v = B2p[lrow * 64 + kt * 4 + quad];
    a2acc = __builtin_amdgcn_mfma_f32_16x16x32_bf16(a2, b2v, a2acc, 0, 0, 0);
  }
  if (lrow < 10) {
    float bb = sb2[lrow];
#pragma unroll
    for (int r = 0; r < 4; r++) xh[w][quad * 4 + r][lrow] = a2acc[r] + bb;
  }
  __syncthreads();

#pragma unroll
  for (int ii = 0; ii < 10; ii++) {
    int item = ii * 64 + l;
    int row = item & 15, o = item >> 4;
    float v = sblr[o];
#pragma unroll
    for (int c = 0; c < 10; c++) v += xh[w][row][c] * sWlr[c * 40 + o];
    int gr = row0 + row;
    if (o < 20) xl[(size_t)gr * 20 + o] = v;
    else        xr[(size_t)gr * 20 + (o - 20)] = v;
  }
}

// ---------------- CSR build stage 1: per-block bucket histogram ----------------
__global__ __launch_bounds__(256) void kB1(const int* __restrict__ ei,
                                           int* __restrict__ gh) {
  __shared__ int h[NB];
  int t = threadIdx.x, blk = blockIdx.x;
  for (int i = t; i < NB; i += 256) h[i] = 0;
  __syncthreads();
  const int* dst = ei + NE;
  int base = blk * ECHUNK, bend = base + ECHUNK;
  for (int i = base + t; i < bend; i += 256)
    atomicAdd(&h[dst[i] >> 8], 1);
  __syncthreads();
  for (int i = t; i < NB; i += 256) gh[i * EBLK + blk] = h[i];
}

// ---------------- CSR build stage 2: scan of (bucket,block) partials ----------------
__global__ __launch_bounds__(256) void kB2(int* __restrict__ gh,
                                           int* __restrict__ bb,
                                           int* __restrict__ offs) {
  __shared__ int pre[256];
  int t = threadIdx.x;
  int base = t * NB;  // NB*EBLK/256 == NB values per thread
  int s = 0;
  for (int i = 0; i < NB; i++) s += gh[base + i];
  pre[t] = s;
  __syncthreads();
  int v = s;
  for (int o = 1; o < 256; o <<= 1) {
    int u = (t >= o) ? pre[t - o] : 0;
    __syncthreads();
    pre[t] += u;
    __syncthreads();
  }
  int run = pre[t] - v;  // exclusive prefix at this thread's range start
  for (int i = 0; i < NB; i++) {
    int idx = base + i;
    int h = gh[idx];
    gh[idx] = run;
    if ((idx & (EBLK - 1)) == 0) bb[idx >> 8] = run;  // EBLK=256
    run += h;
  }
  if (t == 255) { bb[NB] = NE; offs[NN] = NE; }
}

// ---------------- CSR build stage 3: bin edges (coalesced run writes) ----------------
__global__ __launch_bounds__(256) void kB3(const int* __restrict__ ei,
                                           const void* __restrict__ ew,
                                           const int* __restrict__ flags,
                                           const int* __restrict__ gh,
                                           int2* __restrict__ binned) {
  __shared__ int cur[NB];
  const int f32f = flags[0];
  int t = threadIdx.x, blk = blockIdx.x;
  for (int i = t; i < NB; i += 256) cur[i] = gh[i * EBLK + blk];
  __syncthreads();
  int base = blk * ECHUNK, bend = base + ECHUNK;
  for (int i = base + t; i < bend; i += 256) {
    int s = ei[i], d = ei[NE + i];
    float w = LD(ew, i, f32f);
    int b = d >> 8;
    int pos = atomicAdd(&cur[b], 1);
    binned[pos] = make_int2(s | ((d & 255) << 17), __float_as_int(w));
  }
}

// ---------------- CSR build stage 4: per-bucket LDS counting sort (in place) ----------------
__global__ __launch_bounds__(256, 2) void kB4(const int* __restrict__ bb,
                                              int2* __restrict__ bincsr,
                                              int* __restrict__ offs) {
  __shared__ int2 sE[9472];   // +14 sigma of max bucket load
  __shared__ int cnt[256];
  __shared__ int pre[256];
  int t = threadIdx.x, b = blockIdx.x;
  int base = bb[b], end = bb[b + 1];
  int ne = end - base;
  cnt[t] = 0;
  __syncthreads();
  for (int i = t; i < ne; i += 256) {
    int2 e = bincsr[base + i];
    if (i < 9472) sE[i] = e;
    atomicAdd(&cnt[(unsigned)e.x >> 17], 1);
  }
  __syncthreads();
  int v = cnt[t];
  pre[t] = v;
  __syncthreads();
  for (int o = 1; o < 256; o <<= 1) {
    int u = (t >= o) ? pre[t - o] : 0;
    __syncthreads();
    pre[t] += u;
    __syncthreads();
  }
  int ex = pre[t] - v;
  int node = b * 256 + t;
  if (node < NN) offs[node] = base + ex;
  cnt[t] = ex;  // becomes cur
  __syncthreads();
  for (int i = t; i < ne; i += 256) {
    int2 e = (i < 9472) ? sE[i] : bincsr[base + i];  // overflow path statistically unreachable
    int dl = (unsigned)e.x >> 17;
    int pos = atomicAdd(&cnt[dl], 1);
    bincsr[base + pos] = make_int2(e.x & 0x1FFFF, e.y);
  }
}

// ---------------- fused gather + online softmax + aggregate + output GEMM ----------------
__global__ __launch_bounds__(256) void kAgg(
    const int* __restrict__ offs, const int2* __restrict__ csr,
    const float* __restrict__ xl, const float* __restrict__ xr,
    const float* __restrict__ smallf, const float* __restrict__ W34,
    const float* __restrict__ b34, const int* __restrict__ flags,
    void* __restrict__ out)
{
  __shared__ float sW[2560];
  __shared__ float sb[128];
  __shared__ float sAtt[20], sWe[20], sGb[20];
  const int f32f = flags[0];
  int t = threadIdx.x;
  for (int i = t; i < 2560; i += 256) sW[i] = W34[i];
  if (t < 128) sb[t] = b34[t];
  if (t < 20) { sAtt[t] = smallf[SF_ATT + t]; sWe[t] = smallf[SF_WE + t]; sGb[t] = smallf[SF_GB + t]; }
  __syncthreads();

  int w = t >> 6, lane = t & 63;
  int n = blockIdx.x * 4 + w;

  int start = offs[n], end = offs[n + 1];

  float vr[20];
  {
    const float4* pr = (const float4*)(xr + (size_t)n * 20);
#pragma unroll
    for (int i = 0; i < 5; i++) {
      float4 b = pr[i];
      vr[i * 4] = b.x; vr[i * 4 + 1] = b.y; vr[i * 4 + 2] = b.z; vr[i * 4 + 3] = b.w;
    }
  }

  float m0 = -1e30f, l0 = 0.f, m1 = -1e30f, l1 = 0.f;
  float acc0[10], acc1[10];
#pragma unroll
  for (int c = 0; c < 10; c++) { acc0[c] = 0.f; acc1[c] = 0.f; }

  for (int i = start + lane; i < end; i += 64) {
    int2 eg = csr[i];
    int src = eg.x;
    float ww = __int_as_float(eg.y);
    const float4* pl = (const float4*)(xl + (size_t)src * 20);
    float vl[20];
#pragma unroll
    for (int k = 0; k < 5; k++) {
      float4 v = pl[k];
      vl[k * 4] = v.x; vl[k * 4 + 1] = v.y; vl[k * 4 + 2] = v.z; vl[k * 4 + 3] = v.w;
    }
    float a0 = 0.f, a1 = 0.f;
#pragma unroll
    for (int c = 0; c < 20; c++) {
      float v = vl[c] + vr[c] + ww * sWe[c];
      v = fmaxf(v, 0.2f * v);
      if (c < 10) a0 += v * sAtt[c]; else a1 += v * sAtt[c];
    }
    {
      float mn = fmaxf(m0, a0);
      float corr = __expf(m0 - mn), p = __expf(a0 - mn);
      l0 = l0 * corr + p;
#pragma unroll
      for (int c = 0; c < 10; c++) acc0[c] = acc0[c] * corr + p * vl[c];
      m0 = mn;
    }
    {
      float mn = fmaxf(m1, a1);
      float corr = __expf(m1 - mn), p = __expf(a1 - mn);
      l1 = l1 * corr + p;
#pragma unroll
      for (int c = 0; c < 10; c++) acc1[c] = acc1[c] * corr + p * vl[10 + c];
      m1 = mn;
    }
  }

#pragma unroll
  for (int o = 1; o < 64; o <<= 1) {
    float mo = __shfl_xor(m0, o), lo = __shfl_xor(l0, o);
    float mn = fmaxf(m0, mo);
    float ca = __expf(m0 - mn), cb = __expf(mo - mn);
    l0 = l0 * ca + lo * cb;
#pragma unroll
    for (int c = 0; c < 10; c++) acc0[c] = acc0[c] * ca + __shfl_xor(acc0[c], o) * cb;
    m0 = mn;
    float mo1 = __shfl_xor(m1, o), lo1 = __shfl_xor(l1, o);
    float mn1 = fmaxf(m1, mo1);
    float da = __expf(m1 - mn1), db = __expf(mo1 - mn1);
    l1 = l1 * da + lo1 * db;
#pragma unroll
    for (int c = 0; c < 10; c++) acc1[c] = acc1[c] * da + __shfl_xor(acc1[c], o) * db;
    m1 = mn1;
  }

  float g[20];
  float inv0 = 1.f / (l0 + 1e-16f), inv1 = 1.f / (l1 + 1e-16f);
#pragma unroll
  for (int c = 0; c < 10; c++) {
    g[c]      = acc0[c] * inv0 + sGb[c];
    g[10 + c] = acc1[c] * inv1 + sGb[10 + c];
  }

  int col = lane * 2;
  float v0 = sb[col], v1 = sb[col + 1];
#pragma unroll
  for (int j = 0; j < 20; j++) {
    v0 += g[j] * sW[j * 128 + col];
    v1 += g[j] * sW[j * 128 + col + 1];
  }
  size_t oi = (size_t)n * 128 + col;
  if (f32f) {
    ((float2*)out)[oi / 2] = make_float2(v0, v1);
  } else {
    unsigned pk = (unsigned)(unsigned short)f2bf(v0) |
                  ((unsigned)(unsigned short)f2bf(v1) << 16);
    ((unsigned*)out)[oi / 2] = pk;
  }
}

extern "C" void kernel_launch(void* const* d_in, const int* in_sizes, int n_in,
                              void* d_out, int out_size, void* d_ws, size_t ws_size,
                              hipStream_t stream) {
  (void)in_sizes; (void)n_in; (void)out_size; (void)ws_size;
  const void* sig  = d_in[0];
  const int*  ei   = (const int*)d_in[1];
  const void* ew   = d_in[2];
  const void* mask = d_in[3];
  const void* W1   = d_in[4];
  const void* b1   = d_in[5];
  const void* gam  = d_in[6];
  const void* bet  = d_in[7];
  const void* W2   = d_in[8];
  const void* b2   = d_in[9];
  const void* Wl   = d_in[10];
  const void* bl   = d_in[11];
  const void* Wr   = d_in[12];
  const void* br   = d_in[13];
  const void* We   = d_in[14];
  const void* att  = d_in[15];
  const void* gb   = d_in[16];
  const void* W3   = d_in[17];
  const void* b3   = d_in[18];
  const void* W4   = d_in[19];
  const void* b4   = d_in[20];

  char* ws = (char*)d_ws;
  short* W1T    = (short*)(ws + OFF_W1T);
  short* W2T    = (short*)(ws + OFF_W2T);
  float* b1eff  = (float*)(ws + OFF_B1E);
  float* smallf = (float*)(ws + OFF_SMALL);
  float* W34    = (float*)(ws + OFF_W34);
  float* b34    = (float*)(ws + OFF_B34);
  int*   flags  = (int*)(ws + OFF_FLAGS);
  float* xl     = (float*)(ws + OFF_XL);
  float* xr     = (float*)(ws + OFF_XR);
  int*   gh     = (int*)(ws + OFF_GH);
  int*   bb     = (int*)(ws + OFF_BB);
  int*   offs   = (int*)(ws + OFF_OFFS);
  int2*  bincsr = (int2*)(ws + OFF_BIN);

  kDetect<<<1, 64, 0, stream>>>((const unsigned short*)W1, (const unsigned*)mask, flags);
  kPrep<<<301, 256, 0, stream>>>(W1, b1, gam, bet, W2, b2, Wl, bl, Wr, br, We, att,
                                 gb, W3, b3, W4, b4, flags, W1T, b1eff, W2T, smallf, W34, b34);
  kA<<<(NN + 63) / 64, 256, 0, stream>>>(sig, mask, W1T, b1eff, W2T, smallf, flags, xl, xr);
  kB1<<<EBLK, 256, 0, stream>>>(ei, gh);
  kB2<<<1, 256, 0, stream>>>(gh, bb, offs);
  kB3<<<EBLK, 256, 0, stream>>>(ei, ew, flags, gh, bincsr);
  kB4<<<NB, 256, 0, stream>>>(bb, bincsr, offs);
  kAgg<<<NN / 4, 256, 0, stream>>>(offs, bincsr, xl, xr, smallf, W34, b34, flags, d_out);
}

// Round 5
// 561.850 us; speedup vs baseline: 7.7395x; 1.4436x over previous
//
#include <hip/hip_runtime.h>
#include <hip/hip_bf16.h>

// ---------------- problem constants ----------------
constexpr int NN = 100000;   // nodes
constexpr int NE = 3200000;  // edges
constexpr int CYC = 128;     // signal channels
constexpr int NB = 391;      // buckets of 256 nodes
constexpr int EBLK = 256;    // edge-pass blocks
constexpr int ECHUNK = NE / EBLK;  // 12500
constexpr int MSCAN = NB * EBLK;   // 100096 (= 391*256)

// ---------------- workspace layout (bytes) ----------------
#define OFF_W1T    0u          // [512][128] bf16
#define OFF_W2T    131072u     // [16][512]  bf16
#define OFF_B1E    147456u     // [512] f32
#define OFF_SMALL  149504u     // 516 f32
#define OFF_W34    151808u     // [20][128] f32
#define OFF_B34    162048u     // [128] f32
#define OFF_FLAGS  162560u     // ints
#define OFF_XLB    163840u     // [N][32] bf16 (20 used, 64B rows) = 6,400,000
#define OFF_XR     6563840u    // [N][20] f32 = 8,000,000
#define OFF_GH     14563840u   // [NB][EBLK] int = 400,384
#define OFF_BB     14964224u   // [NB+1] int (pad 1600)
#define OFF_BS     14965824u   // scan block sums (98 ints, pad 512)
#define OFF_OFFS   14966336u   // [N+1] int (pad 400,064)
#define OFF_BIN    15366400u   // [E] int2 = 25,600,000 (becomes CSR in place)
// total = 40,966,400 bytes (< proven 51.4 MB)

// smallf float offsets
#define SF_WLR 0
#define SF_BLR 400
#define SF_ATT 440  // [20] h*10+c
#define SF_WE  460
#define SF_GB  480
#define SF_B2  500

typedef __attribute__((ext_vector_type(8))) short bf16x8;
typedef __attribute__((ext_vector_type(4))) float f32x4;

__device__ __forceinline__ float bfu(unsigned short x) {
  return __uint_as_float(((unsigned)x) << 16);
}
__device__ __forceinline__ short f2bf(float f) {
  __hip_bfloat16 h = __float2bfloat16(f);
  return *reinterpret_cast<short*>(&h);
}
__device__ __forceinline__ float LD(const void* p, long i, int f32f) {
  return f32f ? ((const float*)p)[i] : bfu(((const unsigned short*)p)[i]);
}

// ---------------- precompute + integrated dtype detect ----------------
__global__ __launch_bounds__(256) void kPrep(
    const void* __restrict__ W1, const void* __restrict__ b1,
    const void* __restrict__ gamma, const void* __restrict__ beta,
    const void* __restrict__ W2, const void* __restrict__ b2,
    const void* __restrict__ Wl, const void* __restrict__ bl,
    const void* __restrict__ Wr, const void* __restrict__ br,
    const void* __restrict__ We, const void* __restrict__ att,
    const void* __restrict__ gbias, const void* __restrict__ W3,
    const void* __restrict__ b3, const void* __restrict__ W4,
    const void* __restrict__ b4, const void* __restrict__ mask,
    int* __restrict__ flags,
    short* __restrict__ W1T, float* __restrict__ b1eff, short* __restrict__ W2T,
    float* __restrict__ smallf, float* __restrict__ W34, float* __restrict__ b34)
{
  __shared__ int sfl[2];
  int t = threadIdx.x;
  if (t < 64) {  // wave 0: redundant per-block dtype detect (W1 low-u16 exponent test)
    const unsigned short* W1u = (const unsigned short*)W1;
    const unsigned* masku = (const unsigned*)mask;
    int big = 0;
#pragma unroll
    for (int k = 0; k < 8; k++) {
      unsigned e = (W1u[t * 8 + k] >> 7) & 0xFF;
      if (e >= 170) big++;
    }
    int byt = 0;
#pragma unroll
    for (int k = 0; k < 4; k++) if (masku[t * 4 + k] & ~1u) byt = 1;
#pragma unroll
    for (int o = 1; o < 64; o <<= 1) {
      big += __shfl_xor(big, o);
      byt |= __shfl_xor(byt, o);
    }
    if (t == 0) {
      sfl[0] = (big >= 4) ? 1 : 0;
      sfl[1] = byt;
      if (blockIdx.x == 0) { flags[0] = sfl[0]; flags[1] = byt; }
    }
  }
  __syncthreads();
  const int f32f = sfl[0];

  int tid = blockIdx.x * 256 + t;
  const float rs = 0.999995000037f;  // 1/sqrt(1+1e-5)
  if (tid < 65536) {
    int j = tid >> 7, k = tid & 127;
    float s = LD(gamma, j, f32f) * rs;
    W1T[j * 128 + k] = f2bf(LD(W1, k * 512 + j, f32f) * s);
    if (k == 0) b1eff[j] = LD(b1, j, f32f) * s + LD(beta, j, f32f);
  } else if (tid < 73728) {
    int i = tid - 65536;
    int c = i >> 9, k = i & 511;
    W2T[c * 512 + k] = (c < 10) ? f2bf(LD(W2, k * 10 + c, f32f)) : (short)0;
  } else if (tid < 76288) {
    int i = tid - 73728;
    int j = i >> 7, tt = i & 127;
    float acc = 0.f;
    for (int k = 0; k < 512; k++) acc += LD(W3, j * 512 + k, f32f) * LD(W4, k * 128 + tt, f32f);
    W34[j * 128 + tt] = acc;
  } else if (tid < 76416) {
    int tt = tid - 76288;
    float acc = LD(b4, tt, f32f);
    for (int k = 0; k < 512; k++) acc += LD(b3, k, f32f) * LD(W4, k * 128 + tt, f32f);
    b34[tt] = acc;
  } else if (tid < 76932) {
    int i = tid - 76416;
    if (i < 400) {
      int c = i / 40, o = i % 40;
      smallf[SF_WLR + i] = (o < 20) ? LD(Wl, c * 20 + o, f32f) : LD(Wr, c * 20 + (o - 20), f32f);
    } else if (i < 440) {
      int o = i - 400;
      smallf[SF_BLR + o] = (o < 20) ? LD(bl, o, f32f) : LD(br, o - 20, f32f);
    } else if (i < 460) {
      smallf[SF_ATT + (i - 440)] = LD(att, i - 440, f32f);
    } else if (i < 480) {
      smallf[SF_WE + (i - 460)] = LD(We, i - 460, f32f);
    } else if (i < 500) {
      smallf[SF_GB + (i - 480)] = LD(gbias, i - 480, f32f);
    } else {
      int c = i - 500;
      smallf[SF_B2 + c] = (c < 10) ? LD(b2, c, f32f) : 0.f;
    }
  }
}

// ---------------- fused mlp_in + GAT linear transforms ----------------
__global__ __launch_bounds__(256) void kA(
    const void* __restrict__ sig, const void* __restrict__ mask,
    const short* __restrict__ W1T, const float* __restrict__ b1eff,
    const short* __restrict__ W2T, const float* __restrict__ smallf,
    const int* __restrict__ flags,
    unsigned short* __restrict__ xlb, float* __restrict__ xr)
{
  __shared__ short h1[4][16][520];
  __shared__ float xh[4][16][12];
  __shared__ float sWlr[400];
  __shared__ float sblr[40];
  __shared__ float sb1[512];
  __shared__ float sb2[16];

  const int f32f = flags[0];
  const int mk8  = flags[1];
  int t = threadIdx.x;
  for (int i = t; i < 512; i += 256) sb1[i] = b1eff[i];
  for (int i = t; i < 400; i += 256) sWlr[i] = smallf[SF_WLR + i];
  if (t < 40) sblr[t] = smallf[SF_BLR + t];
  if (t < 16) sb2[t] = smallf[SF_B2 + t];
  __syncthreads();

  int w = t >> 6, l = t & 63;
  int lrow = l & 15, quad = l >> 4;
  int row0 = blockIdx.x * 64 + w * 16;
  if (row0 + 16 > NN) row0 = NN - 16;
  int arow = row0 + lrow;

  bool mbit = mk8 ? (((const unsigned char*)mask)[arow] != 0)
                  : (((const int*)mask)[arow] != 0);
  bool keep = !mbit;

  bf16x8 zz = {0, 0, 0, 0, 0, 0, 0, 0};
  bf16x8 af[4];
  if (!keep) {
#pragma unroll
    for (int kt = 0; kt < 4; kt++) af[kt] = zz;
  } else if (f32f) {
    const float4* Sf = (const float4*)((const float*)sig + (size_t)arow * CYC);
#pragma unroll
    for (int kt = 0; kt < 4; kt++) {
      float4 x0 = Sf[kt * 8 + quad * 2];
      float4 x1 = Sf[kt * 8 + quad * 2 + 1];
      bf16x8 v;
      v[0] = f2bf(x0.x); v[1] = f2bf(x0.y); v[2] = f2bf(x0.z); v[3] = f2bf(x0.w);
      v[4] = f2bf(x1.x); v[5] = f2bf(x1.y); v[6] = f2bf(x1.z); v[7] = f2bf(x1.w);
      af[kt] = v;
    }
  } else {
    const bf16x8* Ap = (const bf16x8*)((const unsigned short*)sig + (size_t)arow * CYC);
#pragma unroll
    for (int kt = 0; kt < 4; kt++) af[kt] = Ap[kt * 4 + quad];
  }

  f32x4 acc[32];
#pragma unroll
  for (int ct = 0; ct < 32; ct++) acc[ct] = (f32x4){0.f, 0.f, 0.f, 0.f};
  const bf16x8* Bp = (const bf16x8*)W1T;
#pragma unroll
  for (int kt = 0; kt < 4; kt++) {
#pragma unroll
    for (int ct = 0; ct < 32; ct++) {
      bf16x8 bv = Bp[(ct * 16 + lrow) * 16 + kt * 4 + quad];
      acc[ct] = __builtin_amdgcn_mfma_f32_16x16x32_bf16(af[kt], bv, acc[ct], 0, 0, 0);
    }
  }
#pragma unroll
  for (int ct = 0; ct < 32; ct++) {
    int col = ct * 16 + lrow;
    float bb = sb1[col];
#pragma unroll
    for (int r = 0; r < 4; r++) {
      float v = fmaxf(acc[ct][r] + bb, 0.f);
      h1[w][quad * 4 + r][col] = f2bf(v);
    }
  }
  __syncthreads();

  f32x4 a2acc = (f32x4){0.f, 0.f, 0.f, 0.f};
  const bf16x8* B2p = (const bf16x8*)W2T;
#pragma unroll
  for (int kt = 0; kt < 16; kt++) {
    bf16x8 a2 = *(const bf16x8*)&h1[w][lrow][kt * 32 + quad * 8];
    bf16x8 b2v = B2p[lrow * 64 + kt * 4 + quad];
    a2acc = __builtin_amdgcn_mfma_f32_16x16x32_bf16(a2, b2v, a2acc, 0, 0, 0);
  }
  if (lrow < 10) {
    float bb = sb2[lrow];
#pragma unroll
    for (int r = 0; r < 4; r++) xh[w][quad * 4 + r][lrow] = a2acc[r] + bb;
  }
  __syncthreads();

#pragma unroll
  for (int ii = 0; ii < 10; ii++) {
    int item = ii * 64 + l;
    int row = item & 15, o = item >> 4;
    float v = sblr[o];
#pragma unroll
    for (int c = 0; c < 10; c++) v += xh[w][row][c] * sWlr[c * 40 + o];
    int gr = row0 + row;
    if (o < 20) xlb[(size_t)gr * 32 + o] = (unsigned short)f2bf(v);
    else        xr[(size_t)gr * 20 + (o - 20)] = v;
  }
}

// ---------------- CSR build stage 1: per-block bucket histogram ----------------
__global__ __launch_bounds__(256) void kB1(const int* __restrict__ ei,
                                           int* __restrict__ gh) {
  __shared__ int h[NB];
  int t = threadIdx.x, blk = blockIdx.x;
  for (int i = t; i < NB; i += 256) h[i] = 0;
  __syncthreads();
  const int* dst = ei + NE;
  int base = blk * ECHUNK, bend = base + ECHUNK;
  for (int i = base + t; i < bend; i += 256)
    atomicAdd(&h[dst[i] >> 8], 1);
  __syncthreads();
  for (int i = t; i < NB; i += 256) gh[i * EBLK + blk] = h[i];
}

// ---------------- scan of gh[100096]: 3-kernel multi-block exclusive scan ----------------
__global__ __launch_bounds__(256) void kS1(const int* __restrict__ gh,
                                           int* __restrict__ ghx,
                                           int* __restrict__ bsum) {
  __shared__ int sS[256];
  int t = threadIdx.x;
  int base = blockIdx.x * 1024 + t * 4;
  int d0 = (base     < MSCAN) ? gh[base]     : 0;
  int d1 = (base + 1 < MSCAN) ? gh[base + 1] : 0;
  int d2 = (base + 2 < MSCAN) ? gh[base + 2] : 0;
  int d3 = (base + 3 < MSCAN) ? gh[base + 3] : 0;
  int tsum = d0 + d1 + d2 + d3;
  sS[t] = tsum;
  __syncthreads();
  for (int o = 1; o < 256; o <<= 1) {
    int v = (t >= o) ? sS[t - o] : 0;
    __syncthreads();
    sS[t] += v;
    __syncthreads();
  }
  int ex = sS[t] - tsum;
  if (base     < MSCAN) ghx[base]     = ex;
  if (base + 1 < MSCAN) ghx[base + 1] = ex + d0;
  if (base + 2 < MSCAN) ghx[base + 2] = ex + d0 + d1;
  if (base + 3 < MSCAN) ghx[base + 3] = ex + d0 + d1 + d2;
  if (t == 255) bsum[blockIdx.x] = sS[255];
}

__global__ __launch_bounds__(128) void kS2(int* __restrict__ bsum, int nb) {
  __shared__ int sS[128];
  int t = threadIdx.x;
  int v = (t < nb) ? bsum[t] : 0;
  sS[t] = v;
  __syncthreads();
  for (int o = 1; o < 128; o <<= 1) {
    int u = (t >= o) ? sS[t - o] : 0;
    __syncthreads();
    sS[t] += u;
    __syncthreads();
  }
  if (t < nb) bsum[t] = sS[t] - v;
}

__global__ __launch_bounds__(256) void kS3(int* __restrict__ gh,
                                           const int* __restrict__ bsum,
                                           int* __restrict__ bb,
                                           int* __restrict__ offs) {
  int i = blockIdx.x * 256 + threadIdx.x;  // grid 391*256 == MSCAN exactly
  int v = gh[i] + bsum[i >> 10];
  gh[i] = v;
  if ((i & 255) == 0) bb[i >> 8] = v;
  if (i == 0) { bb[NB] = NE; offs[NN] = NE; }
}

// ---------------- CSR build stage 3: bin edges ----------------
__global__ __launch_bounds__(256) void kB3(const int* __restrict__ ei,
                                           const void* __restrict__ ew,
                                           const int* __restrict__ flags,
                                           const int* __restrict__ gh,
                                           int2* __restrict__ binned) {
  __shared__ int cur[NB];
  const int f32f = flags[0];
  int t = threadIdx.x, blk = blockIdx.x;
  for (int i = t; i < NB; i += 256) cur[i] = gh[i * EBLK + blk];
  __syncthreads();
  int base = blk * ECHUNK, bend = base + ECHUNK;
  for (int i = base + t; i < bend; i += 256) {
    int s = ei[i], d = ei[NE + i];
    float w = LD(ew, i, f32f);
    int b = d >> 8;
    int pos = atomicAdd(&cur[b], 1);
    binned[pos] = make_int2(s | ((d & 255) << 17), __float_as_int(w));
  }
}

// ---------------- CSR build stage 4: per-bucket LDS counting sort ----------------
__global__ __launch_bounds__(256, 2) void kB4(const int* __restrict__ bb,
                                              int2* __restrict__ bincsr,
                                              int* __restrict__ offs) {
  __shared__ int2 sE[9472];
  __shared__ int cnt[256];
  __shared__ int pre[256];
  int t = threadIdx.x, b = blockIdx.x;
  int base = bb[b], end = bb[b + 1];
  int ne = end - base;
  cnt[t] = 0;
  __syncthreads();
  for (int i = t; i < ne; i += 256) {
    int2 e = bincsr[base + i];
    if (i < 9472) sE[i] = e;
    atomicAdd(&cnt[(unsigned)e.x >> 17], 1);
  }
  __syncthreads();
  int v = cnt[t];
  pre[t] = v;
  __syncthreads();
  for (int o = 1; o < 256; o <<= 1) {
    int u = (t >= o) ? pre[t - o] : 0;
    __syncthreads();
    pre[t] += u;
    __syncthreads();
  }
  int ex = pre[t] - v;
  int node = b * 256 + t;
  if (node < NN) offs[node] = base + ex;
  cnt[t] = ex;
  __syncthreads();
  for (int i = t; i < ne; i += 256) {
    int2 e = (i < 9472) ? sE[i] : bincsr[base + i];
    int dl = (unsigned)e.x >> 17;
    int pos = atomicAdd(&cnt[dl], 1);
    bincsr[base + pos] = make_int2(e.x & 0x1FFFF, e.y);
  }
}

// ---------------- fused gather + softmax-agg + output GEMM ----------------
// 16 lanes per node, 16 nodes per block, grid 6250
__global__ __launch_bounds__(256) void kAgg(
    const int* __restrict__ offs, const int2* __restrict__ csr,
    const unsigned short* __restrict__ xlb, const float* __restrict__ xr,
    const float* __restrict__ smallf, const float* __restrict__ W34,
    const float* __restrict__ b34, const int* __restrict__ flags,
    void* __restrict__ out)
{
  __shared__ float sW[2560];
  __shared__ float sb[128];
  __shared__ float sAtt[20], sWe[20], sGb[20];
  const int f32f = flags[0];
  int t = threadIdx.x;
  for (int i = t; i < 2560; i += 256) sW[i] = W34[i];
  if (t < 128) sb[t] = b34[t];
  if (t < 20) { sAtt[t] = smallf[SF_ATT + t]; sWe[t] = smallf[SF_WE + t]; sGb[t] = smallf[SF_GB + t]; }
  __syncthreads();

  int g = t >> 4, sl = t & 15;
  int n = blockIdx.x * 16 + g;
  int start = offs[n], end = offs[n + 1];

  float vr[20];
  {
    const float4* pr = (const float4*)(xr + (size_t)n * 20);
#pragma unroll
    for (int i = 0; i < 5; i++) {
      float4 b = pr[i];
      vr[i * 4] = b.x; vr[i * 4 + 1] = b.y; vr[i * 4 + 2] = b.z; vr[i * 4 + 3] = b.w;
    }
  }

  // direct exp (no max subtraction): softmax is shift-invariant; |alpha| << 88
  float l0 = 0.f, l1 = 0.f;
  float acc[20];
#pragma unroll
  for (int c = 0; c < 20; c++) acc[c] = 0.f;

  for (int i = start + sl; i < end; i += 16) {
    int2 eg = csr[i];
    const unsigned short* p = xlb + (size_t)eg.x * 32;
    uint4 q0 = *(const uint4*)p;             // ch 0..7
    uint4 q1 = *(const uint4*)(p + 8);       // ch 8..15
    uint2 q2 = *(const uint2*)(p + 16);      // ch 16..19
    float vl[20];
    unsigned qq[10] = {q0.x, q0.y, q0.z, q0.w, q1.x, q1.y, q1.z, q1.w, q2.x, q2.y};
#pragma unroll
    for (int k = 0; k < 10; k++) {
      vl[2 * k]     = __uint_as_float(qq[k] << 16);
      vl[2 * k + 1] = __uint_as_float(qq[k] & 0xffff0000u);
    }
    float ww = __int_as_float(eg.y);
    float a0 = 0.f, a1 = 0.f;
#pragma unroll
    for (int c = 0; c < 20; c++) {
      float v = vl[c] + vr[c] + ww * sWe[c];
      v = fmaxf(v, 0.2f * v);
      if (c < 10) a0 += v * sAtt[c]; else a1 += v * sAtt[c];
    }
    float p0 = __expf(a0), p1 = __expf(a1);
    l0 += p0; l1 += p1;
#pragma unroll
    for (int c = 0; c < 10; c++) {
      acc[c]      += p0 * vl[c];
      acc[10 + c] += p1 * vl[10 + c];
    }
  }

  // add-reduce across the 16-lane group
#pragma unroll
  for (int o = 1; o < 16; o <<= 1) {
    l0 += __shfl_xor(l0, o);
    l1 += __shfl_xor(l1, o);
#pragma unroll
    for (int c = 0; c < 20; c++) acc[c] += __shfl_xor(acc[c], o);
  }

  float inv0 = 1.f / (l0 + 1e-16f), inv1 = 1.f / (l1 + 1e-16f);
  float gv[20];
#pragma unroll
  for (int c = 0; c < 10; c++) {
    gv[c]      = acc[c] * inv0 + sGb[c];
    gv[10 + c] = acc[10 + c] * inv1 + sGb[10 + c];
  }

  // out row: lane handles cols sl + 16*j (conflict-free sW banks, coalesced stores)
  float v[8];
#pragma unroll
  for (int j = 0; j < 8; j++) v[j] = sb[sl + 16 * j];
#pragma unroll
  for (int k = 0; k < 20; k++) {
    float gk = gv[k];
#pragma unroll
    for (int j = 0; j < 8; j++) v[j] += gk * sW[k * 128 + sl + 16 * j];
  }
  size_t rb = (size_t)n * 128 + sl;
  if (f32f) {
    float* po = (float*)out;
#pragma unroll
    for (int j = 0; j < 8; j++) po[rb + 16 * j] = v[j];
  } else {
    unsigned short* po = (unsigned short*)out;
#pragma unroll
    for (int j = 0; j < 8; j++) po[rb + 16 * j] = (unsigned short)f2bf(v[j]);
  }
}

extern "C" void kernel_launch(void* const* d_in, const int* in_sizes, int n_in,
                              void* d_out, int out_size, void* d_ws, size_t ws_size,
                              hipStream_t stream) {
  (void)in_sizes; (void)n_in; (void)out_size; (void)ws_size;
  const void* sig  = d_in[0];
  const int*  ei   = (const int*)d_in[1];
  const void* ew   = d_in[2];
  const void* mask = d_in[3];
  const void* W1   = d_in[4];
  const void* b1   = d_in[5];
  const void* gam  = d_in[6];
  const void* bet  = d_in[7];
  const void* W2   = d_in[8];
  const void* b2   = d_in[9];
  const void* Wl   = d_in[10];
  const void* bl   = d_in[11];
  const void* Wr   = d_in[12];
  const void* br   = d_in[13];
  const void* We   = d_in[14];
  const void* att  = d_in[15];
  const void* gb   = d_in[16];
  const void* W3   = d_in[17];
  const void* b3   = d_in[18];
  const void* W4   = d_in[19];
  const void* b4   = d_in[20];

  char* ws = (char*)d_ws;
  short* W1T    = (short*)(ws + OFF_W1T);
  short* W2T    = (short*)(ws + OFF_W2T);
  float* b1eff  = (float*)(ws + OFF_B1E);
  float* smallf = (float*)(ws + OFF_SMALL);
  float* W34    = (float*)(ws + OFF_W34);
  float* b34    = (float*)(ws + OFF_B34);
  int*   flags  = (int*)(ws + OFF_FLAGS);
  unsigned short* xlb = (unsigned short*)(ws + OFF_XLB);
  float* xr     = (float*)(ws + OFF_XR);
  int*   gh     = (int*)(ws + OFF_GH);
  int*   bb     = (int*)(ws + OFF_BB);
  int*   bsum   = (int*)(ws + OFF_BS);
  int*   offs   = (int*)(ws + OFF_OFFS);
  int2*  bincsr = (int2*)(ws + OFF_BIN);

  kPrep<<<301, 256, 0, stream>>>(W1, b1, gam, bet, W2, b2, Wl, bl, Wr, br, We, att,
                                 gb, W3, b3, W4, b4, mask, flags,
                                 W1T, b1eff, W2T, smallf, W34, b34);
  kA<<<(NN + 63) / 64, 256, 0, stream>>>(sig, mask, W1T, b1eff, W2T, smallf, flags, xlb, xr);
  kB1<<<EBLK, 256, 0, stream>>>(ei, gh);
  kS1<<<(MSCAN + 1023) / 1024, 256, 0, stream>>>(gh, gh, bsum);
  kS2<<<1, 128, 0, stream>>>(bsum, (MSCAN + 1023) / 1024);
  kS3<<<MSCAN / 256, 256, 0, stream>>>(gh, bsum, bb, offs);
  kB3<<<EBLK, 256, 0, stream>>>(ei, ew, flags, gh, bincsr);
  kB4<<<NB, 256, 0, stream>>>(bb, bincsr, offs);
  kAgg<<<NN / 16, 256, 0, stream>>>(offs, bincsr, xlb, xr, smallf, W34, b34, flags, d_out);
}

// Round 6
// 508.059 us; speedup vs baseline: 8.5589x; 1.1059x over previous
//
#include <hip/hip_runtime.h>
#include <hip/hip_bf16.h>

// ---------------- problem constants ----------------
constexpr int NN = 100000;   // nodes
constexpr int NE = 3200000;  // edges
constexpr int CYC = 128;     // signal channels
constexpr int NB = 391;      // buckets of 256 nodes
constexpr int EBLK = 256;    // edge-pass blocks
constexpr int ECHUNK = NE / EBLK;  // 12500
constexpr int MSCAN = NB * EBLK;   // 100096

// ---------------- workspace layout (bytes) ----------------
#define OFF_W1T    0u          // [512][128] bf16
#define OFF_W2T    131072u     // [16][512]  bf16
#define OFF_B1E    147456u     // [512] f32
#define OFF_SMALL  149504u     // 516 f32
#define OFF_W34    151808u     // [20][128] f32
#define OFF_B34    162048u     // [128] f32
#define OFF_FLAGS  162560u     // ints
#define OFF_XLB    163840u     // [N][32] bf16 (20 used, 64B rows) = 6,400,000
#define OFF_XR     6563840u    // [N][20] f32 = 8,000,000
#define OFF_GH     14563840u   // [NB][EBLK] int = 400,384
#define OFF_BB     14964224u   // [NB+1] int (pad 1600)
#define OFF_BS     14965824u   // scan block sums (98 ints, pad 512)
#define OFF_OFFS   14966336u   // [N+1] int (pad 400,064)
#define OFF_BIN    15366400u   // [E] int2 = 25,600,000 (becomes CSR in place)
// total = 40,966,400 bytes

// smallf float offsets
#define SF_WLR 0
#define SF_BLR 400
#define SF_ATT 440
#define SF_WE  460
#define SF_GB  480
#define SF_B2  500

typedef __attribute__((ext_vector_type(8))) short bf16x8;
typedef __attribute__((ext_vector_type(4))) float f32x4;

__device__ __forceinline__ float bfu(unsigned short x) {
  return __uint_as_float(((unsigned)x) << 16);
}
__device__ __forceinline__ short f2bf(float f) {
  __hip_bfloat16 h = __float2bfloat16(f);
  return *reinterpret_cast<short*>(&h);
}
__device__ __forceinline__ float LD(const void* p, long i, int f32f) {
  return f32f ? ((const float*)p)[i] : bfu(((const unsigned short*)p)[i]);
}

// ---------------- precompute + integrated dtype detect ----------------
__global__ __launch_bounds__(256) void kPrep(
    const void* __restrict__ W1, const void* __restrict__ b1,
    const void* __restrict__ gamma, const void* __restrict__ beta,
    const void* __restrict__ W2, const void* __restrict__ b2,
    const void* __restrict__ Wl, const void* __restrict__ bl,
    const void* __restrict__ Wr, const void* __restrict__ br,
    const void* __restrict__ We, const void* __restrict__ att,
    const void* __restrict__ gbias, const void* __restrict__ W3,
    const void* __restrict__ b3, const void* __restrict__ W4,
    const void* __restrict__ b4, const void* __restrict__ mask,
    int* __restrict__ flags,
    short* __restrict__ W1T, float* __restrict__ b1eff, short* __restrict__ W2T,
    float* __restrict__ smallf, float* __restrict__ W34, float* __restrict__ b34)
{
  __shared__ int sfl[2];
  int t = threadIdx.x;
  if (t < 64) {
    const unsigned short* W1u = (const unsigned short*)W1;
    const unsigned* masku = (const unsigned*)mask;
    int big = 0;
#pragma unroll
    for (int k = 0; k < 8; k++) {
      unsigned e = (W1u[t * 8 + k] >> 7) & 0xFF;
      if (e >= 170) big++;
    }
    int byt = 0;
#pragma unroll
    for (int k = 0; k < 4; k++) if (masku[t * 4 + k] & ~1u) byt = 1;
#pragma unroll
    for (int o = 1; o < 64; o <<= 1) {
      big += __shfl_xor(big, o);
      byt |= __shfl_xor(byt, o);
    }
    if (t == 0) {
      sfl[0] = (big >= 4) ? 1 : 0;
      sfl[1] = byt;
      if (blockIdx.x == 0) { flags[0] = sfl[0]; flags[1] = byt; }
    }
  }
  __syncthreads();
  const int f32f = sfl[0];

  int tid = blockIdx.x * 256 + t;
  const float rs = 0.999995000037f;  // 1/sqrt(1+1e-5)
  if (tid < 65536) {
    int j = tid >> 7, k = tid & 127;
    float s = LD(gamma, j, f32f) * rs;
    W1T[j * 128 + k] = f2bf(LD(W1, k * 512 + j, f32f) * s);
    if (k == 0) b1eff[j] = LD(b1, j, f32f) * s + LD(beta, j, f32f);
  } else if (tid < 73728) {
    int i = tid - 65536;
    int c = i >> 9, k = i & 511;
    W2T[c * 512 + k] = (c < 10) ? f2bf(LD(W2, k * 10 + c, f32f)) : (short)0;
  } else if (tid < 76288) {
    int i = tid - 73728;
    int j = i >> 7, tt = i & 127;
    float acc = 0.f;
    for (int k = 0; k < 512; k++) acc += LD(W3, j * 512 + k, f32f) * LD(W4, k * 128 + tt, f32f);
    W34[j * 128 + tt] = acc;
  } else if (tid < 76416) {
    int tt = tid - 76288;
    float acc = LD(b4, tt, f32f);
    for (int k = 0; k < 512; k++) acc += LD(b3, k, f32f) * LD(W4, k * 128 + tt, f32f);
    b34[tt] = acc;
  } else if (tid < 76932) {
    int i = tid - 76416;
    if (i < 400) {
      int c = i / 40, o = i % 40;
      smallf[SF_WLR + i] = (o < 20) ? LD(Wl, c * 20 + o, f32f) : LD(Wr, c * 20 + (o - 20), f32f);
    } else if (i < 440) {
      int o = i - 400;
      smallf[SF_BLR + o] = (o < 20) ? LD(bl, o, f32f) : LD(br, o - 20, f32f);
    } else if (i < 460) {
      smallf[SF_ATT + (i - 440)] = LD(att, i - 440, f32f);
    } else if (i < 480) {
      smallf[SF_WE + (i - 460)] = LD(We, i - 460, f32f);
    } else if (i < 500) {
      smallf[SF_GB + (i - 480)] = LD(gbias, i - 480, f32f);
    } else {
      int c = i - 500;
      smallf[SF_B2 + c] = (c < 10) ? LD(b2, c, f32f) : 0.f;
    }
  }
}

// ---------------- fused mlp_in + GAT linear transforms ----------------
// 16 rows/block; 4 waves split the 512 h1 columns (wave w -> cols 128w..128w+127)
// grid = NN/16 = 6250 exactly
__global__ __launch_bounds__(256) void kA(
    const void* __restrict__ sig, const void* __restrict__ mask,
    const short* __restrict__ W1T, const float* __restrict__ b1eff,
    const short* __restrict__ W2T, const float* __restrict__ smallf,
    const int* __restrict__ flags,
    unsigned short* __restrict__ xlb, float* __restrict__ xr)
{
  __shared__ short h1[16][520];      // 16 rows x 512 cols bf16 (pad 8)
  __shared__ float xhp[4][16][16];   // per-wave GEMM2 K-chunk partials
  __shared__ float xh[16][12];
  __shared__ float sWlr[400];
  __shared__ float sblr[40];
  __shared__ float sb1[512];
  __shared__ float sb2[16];

  const int f32f = flags[0];
  const int mk8  = flags[1];
  int t = threadIdx.x;
  for (int i = t; i < 512; i += 256) sb1[i] = b1eff[i];
  for (int i = t; i < 400; i += 256) sWlr[i] = smallf[SF_WLR + i];
  if (t < 40) sblr[t] = smallf[SF_BLR + t];
  if (t < 16) sb2[t] = smallf[SF_B2 + t];
  // no sync yet: first LDS read happens after GEMM1 (sync below covers it)

  int w = t >> 6, l = t & 63;
  int lrow = l & 15, quad = l >> 4;
  int row0 = blockIdx.x * 16;
  int arow = row0 + lrow;

  bool mbit = mk8 ? (((const unsigned char*)mask)[arow] != 0)
                  : (((const int*)mask)[arow] != 0);
  bool keep = !mbit;

  bf16x8 zz = {0, 0, 0, 0, 0, 0, 0, 0};
  bf16x8 af[4];
  if (!keep) {
#pragma unroll
    for (int kt = 0; kt < 4; kt++) af[kt] = zz;
  } else if (f32f) {
    const float4* Sf = (const float4*)((const float*)sig + (size_t)arow * CYC);
#pragma unroll
    for (int kt = 0; kt < 4; kt++) {
      float4 x0 = Sf[kt * 8 + quad * 2];
      float4 x1 = Sf[kt * 8 + quad * 2 + 1];
      bf16x8 v;
      v[0] = f2bf(x0.x); v[1] = f2bf(x0.y); v[2] = f2bf(x0.z); v[3] = f2bf(x0.w);
      v[4] = f2bf(x1.x); v[5] = f2bf(x1.y); v[6] = f2bf(x1.z); v[7] = f2bf(x1.w);
      af[kt] = v;
    }
  } else {
    const bf16x8* Ap = (const bf16x8*)((const unsigned short*)sig + (size_t)arow * CYC);
#pragma unroll
    for (int kt = 0; kt < 4; kt++) af[kt] = Ap[kt * 4 + quad];
  }

  // GEMM1: [16 x 128] @ [128 x 128] per wave (col chunk w)
  f32x4 acc[8];
#pragma unroll
  for (int ct = 0; ct < 8; ct++) acc[ct] = (f32x4){0.f, 0.f, 0.f, 0.f};
  const bf16x8* Bp = (const bf16x8*)W1T;
#pragma unroll
  for (int kt = 0; kt < 4; kt++) {
#pragma unroll
    for (int ct = 0; ct < 8; ct++) {
      bf16x8 bv = Bp[(w * 128 + ct * 16 + lrow) * 16 + kt * 4 + quad];
      acc[ct] = __builtin_amdgcn_mfma_f32_16x16x32_bf16(af[kt], bv, acc[ct], 0, 0, 0);
    }
  }
  __syncthreads();  // sb1 ready; h1 free to write
#pragma unroll
  for (int ct = 0; ct < 8; ct++) {
    int col = w * 128 + ct * 16 + lrow;
    float bb = sb1[col];
#pragma unroll
    for (int r = 0; r < 4; r++) {
      float v = fmaxf(acc[ct][r] + bb, 0.f);
      h1[quad * 4 + r][col] = f2bf(v);
    }
  }
  __syncthreads();

  // GEMM2: [16 x 512] @ [512 x 16]; wave w takes K chunk [128w, 128w+128)
  f32x4 a2acc = (f32x4){0.f, 0.f, 0.f, 0.f};
  const bf16x8* B2p = (const bf16x8*)W2T;
#pragma unroll
  for (int kt2 = 0; kt2 < 4; kt2++) {
    bf16x8 a2 = *(const bf16x8*)&h1[lrow][w * 128 + kt2 * 32 + quad * 8];
    bf16x8 b2v = B2p[lrow * 64 + w * 16 + kt2 * 4 + quad];
    a2acc = __builtin_amdgcn_mfma_f32_16x16x32_bf16(a2, b2v, a2acc, 0, 0, 0);
  }
#pragma unroll
  for (int r = 0; r < 4; r++) xhp[w][quad * 4 + r][lrow] = a2acc[r];
  __syncthreads();

  // reduce K-chunk partials + b2
  for (int i = t; i < 160; i += 256) {
    int row = i / 10, c = i % 10;
    xh[row][c] = xhp[0][row][c] + xhp[1][row][c] + xhp[2][row][c] + xhp[3][row][c] + sb2[c];
  }
  __syncthreads();

  // xl/xr: 16 rows x 40 outputs = 640 items
  for (int i = t; i < 640; i += 256) {
    int row = i & 15, o = i >> 4;
    float v = sblr[o];
#pragma unroll
    for (int c = 0; c < 10; c++) v += xh[row][c] * sWlr[c * 40 + o];
    int gr = row0 + row;
    if (o < 20) xlb[(size_t)gr * 32 + o] = (unsigned short)f2bf(v);
    else        xr[(size_t)gr * 20 + (o - 20)] = v;
  }
}

// ---------------- CSR build stage 1: per-block bucket histogram ----------------
__global__ __launch_bounds__(256) void kB1(const int* __restrict__ ei,
                                           int* __restrict__ gh) {
  __shared__ int h[NB];
  int t = threadIdx.x, blk = blockIdx.x;
  for (int i = t; i < NB; i += 256) h[i] = 0;
  __syncthreads();
  const int* dst = ei + NE;
  int base = blk * ECHUNK, bend = base + ECHUNK;
  for (int i = base + t; i < bend; i += 256)
    atomicAdd(&h[dst[i] >> 8], 1);
  __syncthreads();
  for (int i = t; i < NB; i += 256) gh[i * EBLK + blk] = h[i];
}

// ---------------- scan of gh[100096] ----------------
__global__ __launch_bounds__(256) void kS1(const int* __restrict__ gh,
                                           int* __restrict__ ghx,
                                           int* __restrict__ bsum) {
  __shared__ int sS[256];
  int t = threadIdx.x;
  int base = blockIdx.x * 1024 + t * 4;
  int d0 = (base     < MSCAN) ? gh[base]     : 0;
  int d1 = (base + 1 < MSCAN) ? gh[base + 1] : 0;
  int d2 = (base + 2 < MSCAN) ? gh[base + 2] : 0;
  int d3 = (base + 3 < MSCAN) ? gh[base + 3] : 0;
  int tsum = d0 + d1 + d2 + d3;
  sS[t] = tsum;
  __syncthreads();
  for (int o = 1; o < 256; o <<= 1) {
    int v = (t >= o) ? sS[t - o] : 0;
    __syncthreads();
    sS[t] += v;
    __syncthreads();
  }
  int ex = sS[t] - tsum;
  if (base     < MSCAN) ghx[base]     = ex;
  if (base + 1 < MSCAN) ghx[base + 1] = ex + d0;
  if (base + 2 < MSCAN) ghx[base + 2] = ex + d0 + d1;
  if (base + 3 < MSCAN) ghx[base + 3] = ex + d0 + d1 + d2;
  if (t == 255) bsum[blockIdx.x] = sS[255];
}

__global__ __launch_bounds__(128) void kS2(int* __restrict__ bsum, int nb) {
  __shared__ int sS[128];
  int t = threadIdx.x;
  int v = (t < nb) ? bsum[t] : 0;
  sS[t] = v;
  __syncthreads();
  for (int o = 1; o < 128; o <<= 1) {
    int u = (t >= o) ? sS[t - o] : 0;
    __syncthreads();
    sS[t] += u;
    __syncthreads();
  }
  if (t < nb) bsum[t] = sS[t] - v;
}

__global__ __launch_bounds__(256) void kS3(int* __restrict__ gh,
                                           const int* __restrict__ bsum,
                                           int* __restrict__ bb,
                                           int* __restrict__ offs) {
  int i = blockIdx.x * 256 + threadIdx.x;
  int v = gh[i] + bsum[i >> 10];
  gh[i] = v;
  if ((i & 255) == 0) bb[i >> 8] = v;
  if (i == 0) { bb[NB] = NE; offs[NN] = NE; }
}

// ---------------- CSR build stage 3: bin edges ----------------
__global__ __launch_bounds__(256) void kB3(const int* __restrict__ ei,
                                           const void* __restrict__ ew,
                                           const int* __restrict__ flags,
                                           const int* __restrict__ gh,
                                           int2* __restrict__ binned) {
  __shared__ int cur[NB];
  const int f32f = flags[0];
  int t = threadIdx.x, blk = blockIdx.x;
  for (int i = t; i < NB; i += 256) cur[i] = gh[i * EBLK + blk];
  __syncthreads();
  int base = blk * ECHUNK, bend = base + ECHUNK;
  for (int i = base + t; i < bend; i += 256) {
    int s = ei[i], d = ei[NE + i];
    float w = LD(ew, i, f32f);
    int b = d >> 8;
    int pos = atomicAdd(&cur[b], 1);
    binned[pos] = make_int2(s | ((d & 255) << 17), __float_as_int(w));
  }
}

// ---------------- CSR build stage 4: per-bucket LDS counting sort ----------------
__global__ __launch_bounds__(256, 2) void kB4(const int* __restrict__ bb,
                                              int2* __restrict__ bincsr,
                                              int* __restrict__ offs) {
  __shared__ int2 sE[9472];
  __shared__ int cnt[256];
  __shared__ int pre[256];
  int t = threadIdx.x, b = blockIdx.x;
  int base = bb[b], end = bb[b + 1];
  int ne = end - base;
  cnt[t] = 0;
  __syncthreads();
  for (int i = t; i < ne; i += 256) {
    int2 e = bincsr[base + i];
    if (i < 9472) sE[i] = e;
    atomicAdd(&cnt[(unsigned)e.x >> 17], 1);
  }
  __syncthreads();
  int v = cnt[t];
  pre[t] = v;
  __syncthreads();
  for (int o = 1; o < 256; o <<= 1) {
    int u = (t >= o) ? pre[t - o] : 0;
    __syncthreads();
    pre[t] += u;
    __syncthreads();
  }
  int ex = pre[t] - v;
  int node = b * 256 + t;
  if (node < NN) offs[node] = base + ex;
  cnt[t] = ex;
  __syncthreads();
  for (int i = t; i < ne; i += 256) {
    int2 e = (i < 9472) ? sE[i] : bincsr[base + i];
    int dl = (unsigned)e.x >> 17;
    int pos = atomicAdd(&cnt[dl], 1);
    bincsr[base + pos] = make_int2(e.x & 0x1FFFF, e.y);
  }
}

// ---------------- fused gather + softmax-agg + output GEMM ----------------
__global__ __launch_bounds__(256) void kAgg(
    const int* __restrict__ offs, const int2* __restrict__ csr,
    const unsigned short* __restrict__ xlb, const float* __restrict__ xr,
    const float* __restrict__ smallf, const float* __restrict__ W34,
    const float* __restrict__ b34, const int* __restrict__ flags,
    void* __restrict__ out)
{
  __shared__ float sW[2560];
  __shared__ float sb[128];
  __shared__ float sAtt[20], sWe[20], sGb[20];
  const int f32f = flags[0];
  int t = threadIdx.x;
  for (int i = t; i < 2560; i += 256) sW[i] = W34[i];
  if (t < 128) sb[t] = b34[t];
  if (t < 20) { sAtt[t] = smallf[SF_ATT + t]; sWe[t] = smallf[SF_WE + t]; sGb[t] = smallf[SF_GB + t]; }
  __syncthreads();

  int g = t >> 4, sl = t & 15;
  int n = blockIdx.x * 16 + g;
  int start = offs[n], end = offs[n + 1];

  float vr[20];
  {
    const float4* pr = (const float4*)(xr + (size_t)n * 20);
#pragma unroll
    for (int i = 0; i < 5; i++) {
      float4 b = pr[i];
      vr[i * 4] = b.x; vr[i * 4 + 1] = b.y; vr[i * 4 + 2] = b.z; vr[i * 4 + 3] = b.w;
    }
  }

  float l0 = 0.f, l1 = 0.f;
  float acc[20];
#pragma unroll
  for (int c = 0; c < 20; c++) acc[c] = 0.f;

  for (int i = start + sl; i < end; i += 16) {
    int2 eg = csr[i];
    const unsigned short* p = xlb + (size_t)eg.x * 32;
    uint4 q0 = *(const uint4*)p;
    uint4 q1 = *(const uint4*)(p + 8);
    uint2 q2 = *(const uint2*)(p + 16);
    float vl[20];
    unsigned qq[10] = {q0.x, q0.y, q0.z, q0.w, q1.x, q1.y, q1.z, q1.w, q2.x, q2.y};
#pragma unroll
    for (int k = 0; k < 10; k++) {
      vl[2 * k]     = __uint_as_float(qq[k] << 16);
      vl[2 * k + 1] = __uint_as_float(qq[k] & 0xffff0000u);
    }
    float ww = __int_as_float(eg.y);
    float a0 = 0.f, a1 = 0.f;
#pragma unroll
    for (int c = 0; c < 20; c++) {
      float v = vl[c] + vr[c] + ww * sWe[c];
      v = fmaxf(v, 0.2f * v);
      if (c < 10) a0 += v * sAtt[c]; else a1 += v * sAtt[c];
    }
    float p0 = __expf(a0), p1 = __expf(a1);
    l0 += p0; l1 += p1;
#pragma unroll
    for (int c = 0; c < 10; c++) {
      acc[c]      += p0 * vl[c];
      acc[10 + c] += p1 * vl[10 + c];
    }
  }

#pragma unroll
  for (int o = 1; o < 16; o <<= 1) {
    l0 += __shfl_xor(l0, o);
    l1 += __shfl_xor(l1, o);
#pragma unroll
    for (int c = 0; c < 20; c++) acc[c] += __shfl_xor(acc[c], o);
  }

  float inv0 = 1.f / (l0 + 1e-16f), inv1 = 1.f / (l1 + 1e-16f);
  float gv[20];
#pragma unroll
  for (int c = 0; c < 10; c++) {
    gv[c]      = acc[c] * inv0 + sGb[c];
    gv[10 + c] = acc[10 + c] * inv1 + sGb[10 + c];
  }

  float v[8];
#pragma unroll
  for (int j = 0; j < 8; j++) v[j] = sb[sl + 16 * j];
#pragma unroll
  for (int k = 0; k < 20; k++) {
    float gk = gv[k];
#pragma unroll
    for (int j = 0; j < 8; j++) v[j] += gk * sW[k * 128 + sl + 16 * j];
  }
  size_t rb = (size_t)n * 128 + sl;
  if (f32f) {
    float* po = (float*)out;
#pragma unroll
    for (int j = 0; j < 8; j++) po[rb + 16 * j] = v[j];
  } else {
    unsigned short* po = (unsigned short*)out;
#pragma unroll
    for (int j = 0; j < 8; j++) po[rb + 16 * j] = (unsigned short)f2bf(v[j]);
  }
}

extern "C" void kernel_launch(void* const* d_in, const int* in_sizes, int n_in,
                              void* d_out, int out_size, void* d_ws, size_t ws_size,
                              hipStream_t stream) {
  (void)in_sizes; (void)n_in; (void)out_size; (void)ws_size;
  const void* sig  = d_in[0];
  const int*  ei   = (const int*)d_in[1];
  const void* ew   = d_in[2];
  const void* mask = d_in[3];
  const void* W1   = d_in[4];
  const void* b1   = d_in[5];
  const void* gam  = d_in[6];
  const void* bet  = d_in[7];
  const void* W2   = d_in[8];
  const void* b2   = d_in[9];
  const void* Wl   = d_in[10];
  const void* bl   = d_in[11];
  const void* Wr   = d_in[12];
  const void* br   = d_in[13];
  const void* We   = d_in[14];
  const void* att  = d_in[15];
  const void* gb   = d_in[16];
  const void* W3   = d_in[17];
  const void* b3   = d_in[18];
  const void* W4   = d_in[19];
  const void* b4   = d_in[20];

  char* ws = (char*)d_ws;
  short* W1T    = (short*)(ws + OFF_W1T);
  short* W2T    = (short*)(ws + OFF_W2T);
  float* b1eff  = (float*)(ws + OFF_B1E);
  float* smallf = (float*)(ws + OFF_SMALL);
  float* W34    = (float*)(ws + OFF_W34);
  float* b34    = (float*)(ws + OFF_B34);
  int*   flags  = (int*)(ws + OFF_FLAGS);
  unsigned short* xlb = (unsigned short*)(ws + OFF_XLB);
  float* xr     = (float*)(ws + OFF_XR);
  int*   gh     = (int*)(ws + OFF_GH);
  int*   bb     = (int*)(ws + OFF_BB);
  int*   bsum   = (int*)(ws + OFF_BS);
  int*   offs   = (int*)(ws + OFF_OFFS);
  int2*  bincsr = (int2*)(ws + OFF_BIN);

  kPrep<<<301, 256, 0, stream>>>(W1, b1, gam, bet, W2, b2, Wl, bl, Wr, br, We, att,
                                 gb, W3, b3, W4, b4, mask, flags,
                                 W1T, b1eff, W2T, smallf, W34, b34);
  kA<<<NN / 16, 256, 0, stream>>>(sig, mask, W1T, b1eff, W2T, smallf, flags, xlb, xr);
  kB1<<<EBLK, 256, 0, stream>>>(ei, gh);
  kS1<<<(MSCAN + 1023) / 1024, 256, 0, stream>>>(gh, gh, bsum);
  kS2<<<1, 128, 0, stream>>>(bsum, (MSCAN + 1023) / 1024);
  kS3<<<MSCAN / 256, 256, 0, stream>>>(gh, bsum, bb, offs);
  kB3<<<EBLK, 256, 0, stream>>>(ei, ew, flags, gh, bincsr);
  kB4<<<NB, 256, 0, stream>>>(bb, bincsr, offs);
  kAgg<<<NN / 16, 256, 0, stream>>>(offs, bincsr, xlb, xr, smallf, W34, b34, flags, d_out);
}